// Round 7
// baseline (508.056 us; speedup 1.0000x reference)
//
#include <hip/hip_runtime.h>
#include <math.h>

#define NN 50000
#define NE 800000
#define NPREB 1024   // k_pre grid (blocks); norm_part rows

typedef __attribute__((ext_vector_type(8))) short short8;
typedef __attribute__((ext_vector_type(4))) float floatx4;

__device__ __forceinline__ unsigned short bf16_of(float x) {
  unsigned u = __float_as_uint(x);
  u += 0x7fffu + ((u >> 16) & 1u);
  return (unsigned short)(u >> 16);
}
__device__ __forceinline__ float bf2f(unsigned short u) {
  return __uint_as_float(((unsigned)u) << 16);
}
__device__ __forceinline__ unsigned pack_bf(float a, float b) {
  unsigned ua = __float_as_uint(a); ua += 0x7fffu + ((ua >> 16) & 1u);
  unsigned ub = __float_as_uint(b); ub += 0x7fffu + ((ub >> 16) & 1u);
  return (ua >> 16) | (ub & 0xffff0000u);
}
__device__ __forceinline__ float blo(unsigned w) { return __uint_as_float(w << 16); }
__device__ __forceinline__ float bhi(unsigned w) { return __uint_as_float(w & 0xffff0000u); }

// ---------- k_pre: weight conversion + radial-norm partials + degree count ----------
__global__ __launch_bounds__(256)
void k_pre(const float* __restrict__ coord, const int* __restrict__ row,
           const int* __restrict__ col, const float* __restrict__ Wkv,
           const float* __restrict__ W1, const float* __restrict__ Wq,
           float* __restrict__ norm_part, int* __restrict__ deg,
           unsigned short* __restrict__ Bkvb, unsigned short* __restrict__ W1tb,
           unsigned* __restrict__ Wqp) {
  __shared__ float nred[4][16];
  const int gid = blockIdx.x * 256 + threadIdx.x;
  const int np = gridDim.x * 256;
  for (int idx = gid; idx < 128 * 96; idx += np) {
    int n = idx & 127, kk = idx >> 7;
    float w = (n < 64) ? Wkv[kk * 128 + 2 * n] : Wkv[kk * 128 + 2 * (n - 64) + 1];
    Bkvb[n * 104 + kk] = bf16_of(w);
  }
  for (int idx = gid; idx < 64 * 64; idx += np) {
    int n = idx & 63, kk = idx >> 6;
    W1tb[n * 88 + kk] = bf16_of(W1[kk * 64 + n]);
  }
  for (int idx = gid; idx < 32 * 64; idx += np) {
    int i2 = idx >> 6, j = idx & 63;
    Wqp[idx] = pack_bf(Wq[(2 * i2) * 64 + j], Wq[(2 * i2 + 1) * 64 + j]);
  }
  const int lane = threadIdx.x & 63;
  const int grp = lane >> 4, g = lane & 15;
  const int c4 = g >> 2, f4 = g & 3;
  const int wid = blockIdx.x * 4 + (threadIdx.x >> 6);
  const int nw = gridDim.x * 4;
  float acc = 0.f;
  for (int base = wid * 4; base < NE; base += nw * 4) {
    int e = base + grp;
    int r = row[e], c = col[e];
    float cd = 0.f;
    if (g < 12) cd = coord[r * 12 + g] - coord[c * 12 + g];
    float rad = 0.f;
#pragma unroll
    for (int d = 0; d < 3; ++d)
      rad += __shfl(cd, grp * 16 + c4 * 3 + d) * __shfl(cd, grp * 16 + f4 * 3 + d);
    acc += rad * rad;
    if (g == 0) atomicAdd(deg + r, 1);
  }
  acc += __shfl_xor(acc, 16);
  acc += __shfl_xor(acc, 32);
  if (lane < 16) nred[threadIdx.x >> 6][lane] = acc;
  __syncthreads();
  if (threadIdx.x < 16) {
    float s = nred[0][threadIdx.x] + nred[1][threadIdx.x] +
              nred[2][threadIdx.x] + nred[3][threadIdx.x];
    norm_part[blockIdx.x * 16 + threadIdx.x] = s;
  }
}

// ---------- k_scanq: block 0 = norm reduce + CSR scan; blocks >=1 = q/hb ----------
__global__ __launch_bounds__(1024)
void k_scanq(const int* __restrict__ deg, int* __restrict__ startA,
             int* __restrict__ cursor, const float* __restrict__ norm_part,
             float* __restrict__ rnorm, const float* __restrict__ h,
             const unsigned* __restrict__ Wqp, const float* __restrict__ bq,
             unsigned short* __restrict__ qg2, unsigned short* __restrict__ hb) {
  __shared__ int part[1024];
  __shared__ float nr[64][16];
  __shared__ unsigned sWqp[32 * 64];
  __shared__ float sHr[16][64];
  const int t = threadIdx.x;
  if (blockIdx.x == 0) {
    {  // reduce norm_part[NPREB][16] -> rnorm[16], no atomics
      const int i = t >> 4, c = t & 15;
      float s = 0.f;
#pragma unroll
      for (int j = 0; j < 16; ++j) s += norm_part[((i + 64 * j) << 4) + c];
      nr[i][c] = s;
    }
    __syncthreads();
    if (t < 16) {
      float s = 0.f;
#pragma unroll 8
      for (int i = 0; i < 64; ++i) s += nr[i][t];
      rnorm[t] = 1.0f / fmaxf(sqrtf(s), 1e-12f);
    }
    const int CH = (NN + 1023) / 1024;
    const int lo = t * CH, hi = (lo + CH < NN) ? lo + CH : NN;
    int s = 0;
    for (int i = lo; i < hi; ++i) s += deg[i];
    part[t] = s;
    __syncthreads();
    for (int off = 1; off < 1024; off <<= 1) {
      int v = (t >= off) ? part[t - off] : 0;
      __syncthreads();
      part[t] += v;
      __syncthreads();
    }
    int base = (t == 0) ? 0 : part[t - 1];
    for (int i = lo; i < hi; ++i) {
      startA[i] = base; cursor[i] = base; base += deg[i];
    }
    if (t == 1023) startA[NN] = base;
    return;
  }
  for (int idx = t; idx < 2048; idx += 1024) sWqp[idx] = Wqp[idx];
  __syncthreads();
  const int wv = t >> 6, lane = t & 63;
  const int node = (blockIdx.x - 1) * 16 + wv;
  float hv = h[(size_t)node * 64 + lane];
  sHr[wv][lane] = hv;
  hb[(size_t)node * 64 + lane] = bf16_of(hv);
  float q = bq[lane];
  const float2* hp = (const float2*)sHr[wv];
#pragma unroll 8
  for (int i2 = 0; i2 < 32; ++i2) {
    unsigned w = sWqp[i2 * 64 + lane];
    float2 hbv = hp[i2];
    q += hbv.x * blo(w) + hbv.y * bhi(w);
  }
  qg2[(size_t)node * 64 + (lane & 15) * 4 + (lane >> 4)] = bf16_of(q);
}

// ---------- k_scatter: producer-side permute + per-edge radial/cd record ----
// Runs AFTER k_scanq, so rnorm is ready. Emits one 64B (full-line, no RMW)
// record per permuted slot: [rad*rn bf16 x16 | cd bf16 x12 | row<<16|col | pad]
// Moves the coord gather + radial einsum OUT of k_kv's barrier-fenced phase 1.
__global__ void k_scatter(const int* __restrict__ row, const int* __restrict__ col,
                          const float* __restrict__ edge_attr,
                          const float* __restrict__ coord,
                          const float* __restrict__ rnorm,
                          int* __restrict__ cursor, int* __restrict__ iperm,
                          uint4* __restrict__ rec, uint4* __restrict__ eab) {
  int e = blockIdx.x * 256 + threadIdx.x;
  if (e >= NE) return;
  int r = row[e], c = col[e];
  int p = atomicAdd(cursor + r, 1);
  iperm[e] = p;   // coalesced; lets k_fin write att coalesced
  // edge_attr -> bf16, scatter 32B
  {
    const float4* ep = (const float4*)(edge_attr + (size_t)e * 16);
    float4 f0 = ep[0], f1 = ep[1], f2 = ep[2], f3 = ep[3];
    uint4 a, b;
    a.x = pack_bf(f0.x, f0.y); a.y = pack_bf(f0.z, f0.w);
    a.z = pack_bf(f1.x, f1.y); a.w = pack_bf(f1.z, f1.w);
    b.x = pack_bf(f2.x, f2.y); b.y = pack_bf(f2.z, f2.w);
    b.z = pack_bf(f3.x, f3.y); b.w = pack_bf(f3.z, f3.w);
    eab[(size_t)p * 2]     = a;
    eab[(size_t)p * 2 + 1] = b;
  }
  // coord_diff fp32 (coord rows are 48B, 16B-aligned)
  float cd[12];
  {
    const float4* cr = (const float4*)(coord + (size_t)r * 12);
    const float4* cc = (const float4*)(coord + (size_t)c * 12);
#pragma unroll
    for (int q = 0; q < 3; ++q) {
      float4 a = cr[q], b = cc[q];
      cd[q * 4 + 0] = a.x - b.x; cd[q * 4 + 1] = a.y - b.y;
      cd[q * 4 + 2] = a.z - b.z; cd[q * 4 + 3] = a.w - b.w;
    }
  }
  float rn[16];
  {
    const float4* rp = (const float4*)rnorm;
#pragma unroll
    for (int q = 0; q < 4; ++q) {
      float4 v = rp[q];
      rn[q * 4] = v.x; rn[q * 4 + 1] = v.y; rn[q * 4 + 2] = v.z; rn[q * 4 + 3] = v.w;
    }
  }
  // rad[g]=sum_d cd[c4*3+d]*cd[f4*3+d], g=c4*4+f4; single bf16 rounding of rad*rn
  unsigned rw[8];
#pragma unroll
  for (int g = 0; g < 16; g += 2) {
    int c40 = g >> 2, f40 = g & 3;
    int c41 = (g + 1) >> 2, f41 = (g + 1) & 3;
    float v0 = cd[c40 * 3] * cd[f40 * 3] + cd[c40 * 3 + 1] * cd[f40 * 3 + 1] +
               cd[c40 * 3 + 2] * cd[f40 * 3 + 2];
    float v1 = cd[c41 * 3] * cd[f41 * 3] + cd[c41 * 3 + 1] * cd[f41 * 3 + 1] +
               cd[c41 * 3 + 2] * cd[f41 * 3 + 2];
    rw[g >> 1] = pack_bf(v0 * rn[g], v1 * rn[g + 1]);
  }
  unsigned cw[6];
#pragma unroll
  for (int w = 0; w < 6; ++w) cw[w] = pack_bf(cd[2 * w], cd[2 * w + 1]);
  uint4* rp4 = rec + (size_t)p * 4;
  uint4 q0, q1, q2, q3;
  q0.x = rw[0]; q0.y = rw[1]; q0.z = rw[2]; q0.w = rw[3];
  q1.x = rw[4]; q1.y = rw[5]; q1.z = rw[6]; q1.w = rw[7];
  q2.x = cw[0]; q2.y = cw[1]; q2.z = cw[2]; q2.w = cw[3];
  q3.x = cw[4]; q3.y = cw[5]; q3.z = ((unsigned)r << 16) | (unsigned)c; q3.w = 0;
  rp4[0] = q0; rp4[1] = q1; rp4[2] = q2; rp4[3] = q3;
}

// -------- main fused kernel: GEMM + per-wave segment reduce + atomics -------
// 512 threads / 128 edges, LDS 53,760 B -> 3 blocks/CU. Phase 1 now fully
// coalesced (64B record/edge from k_scatter); radial einsum + coord gather
// deleted. cd rides in 2 regs (rj=2,3 threads) through GEMM1, parked into
// sB's free tail (past the 11,264B W1 overlay) at the overlay barrier.
__global__ __launch_bounds__(512, 6)
void k_kv(const unsigned short* __restrict__ hb,
          const uint4* __restrict__ rec, const uint4* __restrict__ eab,
          const float* __restrict__ bkv, const float* __restrict__ b1,
          const float* __restrict__ W2,
          const unsigned short* __restrict__ Bkvb,
          const unsigned short* __restrict__ W1tb,
          const unsigned short* __restrict__ qg2,
          float* __restrict__ exg, float* __restrict__ l_g,
          float* __restrict__ hacc_g, float* __restrict__ cacc_g) {
  __shared__ __align__(16) unsigned short sA[128][104];   // rad|h|ea bf16; later v
  __shared__ __align__(16) unsigned short sB[128][104];   // [k|v]^T; later W1^T + cd
  __shared__ unsigned sRC[128];                           // row<<16 | col
  unsigned short (*sW1t)[88] = (unsigned short (*)[88])&sB[0][0];
  unsigned short (*sCD)[16] =
      (unsigned short (*)[16])((char*)&sB[0][0] + 64 * 88 * 2);  // 4KB in sB tail

  const int tid = threadIdx.x;
  const int base = blockIdx.x * 128;

  // prefetch W1^T (11,264 B) into registers; parked into sB's space post-GEMM1
  const uint4* gw = (const uint4*)W1tb;
  uint4 w1a = gw[tid];                 // 704 uint4 total; tid<512 all valid
  uint4 w1b;
  if (tid < 192) w1b = gw[512 + tid];

  // record staging: 1 coalesced uint4/thread (512 = 128 records x 4)
  uint4 rw = rec[(size_t)base * 4 + tid];
  const int rs = tid >> 2, rj = tid & 3;
  if (rj == 0)      *(uint4*)&sA[rs][0] = rw;    // rad*rn cols 0..7
  else if (rj == 1) *(uint4*)&sA[rs][8] = rw;    // rad*rn cols 8..15
  else if (rj == 3) sRC[rs] = rw.z;              // row|col (keeps rw.x/.y = cd 8..11)
  // rj==2 keeps rw = cd cols 0..7 in regs until the overlay barrier

  if (tid < 256) {                               // edge_attr bf16, coalesced
    int s = tid >> 1;
    *(uint4*)&sA[s][80 + (tid & 1) * 8] = eab[(size_t)base * 2 + tid];
  }
  {
    const uint4* gb = (const uint4*)Bkvb;
    uint4* sb = (uint4*)&sB[0][0];
    for (int idx = tid; idx < 1664; idx += 512) sb[idx] = gb[idx];
  }
  __syncthreads();   // sRC + sA(rad,ea) + sB visible

  for (int idx = tid; idx < 1024; idx += 512) {
    int s = idx >> 3, k8 = idx & 7;
    unsigned c = sRC[s] & 0xffffu;
    uint4 u = ((const uint4*)(hb + (size_t)c * 64))[k8];
    *(uint4*)&sA[s][16 + k8 * 8] = u;
  }
  __syncthreads();   // sA complete

  const int wv = tid >> 6, lane = tid & 63;
  const int m16 = lane & 15, quad = lane >> 4;
  const int arow = 16 * wv + m16;

  // kv = feat @ [Wk|Wv]
  floatx4 acc[8];
#pragma unroll
  for (int i = 0; i < 8; ++i) acc[i] = (floatx4){0.f, 0.f, 0.f, 0.f};
#pragma unroll
  for (int ks = 0; ks < 3; ++ks) {
    short8 af = *(const short8*)&sA[arow][ks * 32 + quad * 8];
#pragma unroll
    for (int nt = 0; nt < 8; ++nt) {
      short8 bf = *(const short8*)&sB[nt * 16 + m16][ks * 32 + quad * 8];
      acc[nt] = __builtin_amdgcn_mfma_f32_16x16x32_bf16(af, bf, acc[nt], 0, 0, 0);
    }
  }
#pragma unroll
  for (int nt = 0; nt < 4; ++nt) {
    float bk = bkv[2 * (m16 + 16 * nt)];
    float bv = bkv[2 * (m16 + 16 * nt) + 1];
#pragma unroll
    for (int r = 0; r < 4; ++r) { acc[nt][r] += bk; acc[nt + 4][r] += bv; }
  }
  // alpha = q . k -> ex = exp(alpha)   (no max stabilizer: |alpha| << 88)
  float part[4] = {0.f, 0.f, 0.f, 0.f};
#pragma unroll
  for (int r = 0; r < 4; ++r) {
    unsigned nrow = sRC[16 * wv + quad * 4 + r] >> 16;
    uint2 qp = *(const uint2*)(qg2 + (size_t)nrow * 64 + m16 * 4);
    part[r] += blo(qp.x) * acc[0][r] + bhi(qp.x) * acc[1][r] +
               blo(qp.y) * acc[2][r] + bhi(qp.y) * acc[3][r];
  }
#pragma unroll
  for (int off = 1; off < 16; off <<= 1) {
#pragma unroll
    for (int r = 0; r < 4; ++r) part[r] += __shfl_xor(part[r], off);
  }
  float ex[4];
#pragma unroll
  for (int r = 0; r < 4; ++r) ex[r] = __expf(part[r]);
  if (m16 == 0) {
#pragma unroll
    for (int r = 0; r < 4; ++r)
      exg[base + 16 * wv + quad * 4 + r] = ex[r];
  }
  // v (bf16) -> sA rows (wave-private) for the W1 GEMM; keep fp32 v in acc[4..7]
#pragma unroll
  for (int nt = 0; nt < 4; ++nt)
#pragma unroll
    for (int r = 0; r < 4; ++r)
      sA[16 * wv + quad * 4 + r][m16 + 16 * nt] = bf16_of(acc[4 + nt][r]);

  __syncthreads();   // all waves done reading sB (GEMM1)
  {                  // overlay W1^T into sB from regs; park cd into sB tail
    unsigned short* sw = &sB[0][0];
    *(uint4*)&sw[(size_t)tid * 8] = w1a;
    if (tid < 192) *(uint4*)&sw[(size_t)(512 + tid) * 8] = w1b;
    if (rj == 2) *(uint4*)&sCD[rs][0] = rw;        // cd cols 0..7
    else if (rj == 3) {
      uint2 t2; t2.x = rw.x; t2.y = rw.y;
      *(uint2*)&sCD[rs][8] = t2;                   // cd cols 8..11
    }
  }
  __syncthreads();   // sW1t + sCD visible

  // t = silu(v @ W1 + b1)
  floatx4 tacc[4];
#pragma unroll
  for (int i = 0; i < 4; ++i) tacc[i] = (floatx4){0.f, 0.f, 0.f, 0.f};
#pragma unroll
  for (int ks = 0; ks < 2; ++ks) {
    short8 af = *(const short8*)&sA[arow][ks * 32 + quad * 8];
#pragma unroll
    for (int nt = 0; nt < 4; ++nt) {
      short8 bf = *(const short8*)&sW1t[nt * 16 + m16][ks * 32 + quad * 8];
      tacc[nt] = __builtin_amdgcn_mfma_f32_16x16x32_bf16(af, bf, tacc[nt], 0, 0, 0);
    }
  }
#pragma unroll
  for (int nt = 0; nt < 4; ++nt) {
    float bb = b1[m16 + 16 * nt];
#pragma unroll
    for (int r = 0; r < 4; ++r) {
      float t = tacc[nt][r] + bb;
      tacc[nt][r] = t * __builtin_amdgcn_rcpf(1.f + __expf(-t));  // silu, rcp
    }
  }
  // cv = t @ W2 : local partials, then 16-lane REDUCE-SCATTER (15 shfl)
  float w0[16];   // j = r*4+c
#pragma unroll
  for (int r = 0; r < 4; ++r)
#pragma unroll
    for (int c = 0; c < 4; ++c) w0[r * 4 + c] = 0.f;
#pragma unroll
  for (int nt = 0; nt < 4; ++nt) {
    float4 w2r = ((const float4*)W2)[m16 + 16 * nt];
#pragma unroll
    for (int r = 0; r < 4; ++r) {
      w0[r * 4 + 0] += tacc[nt][r] * w2r.x;
      w0[r * 4 + 1] += tacc[nt][r] * w2r.y;
      w0[r * 4 + 2] += tacc[nt][r] * w2r.z;
      w0[r * 4 + 3] += tacc[nt][r] * w2r.w;
    }
  }
  float rs1[8];
#pragma unroll
  for (int jj = 0; jj < 8; ++jj) {
    float snd = (m16 & 8) ? w0[jj] : w0[jj + 8];
    float rcv = __shfl_xor(snd, 8);
    rs1[jj] = ((m16 & 8) ? w0[jj + 8] : w0[jj]) + rcv;
  }
  float rs2[4];
#pragma unroll
  for (int jj = 0; jj < 4; ++jj) {
    float snd = (m16 & 4) ? rs1[jj] : rs1[jj + 4];
    float rcv = __shfl_xor(snd, 4);
    rs2[jj] = ((m16 & 4) ? rs1[jj + 4] : rs1[jj]) + rcv;
  }
  float rs3[2];
#pragma unroll
  for (int jj = 0; jj < 2; ++jj) {
    float snd = (m16 & 2) ? rs2[jj] : rs2[jj + 2];
    float rcv = __shfl_xor(snd, 2);
    rs3[jj] = ((m16 & 2) ? rs2[jj + 2] : rs2[jj]) + rcv;
  }
  float cvtot;
  {
    float snd = (m16 & 1) ? rs3[0] : rs3[1];
    float rcv = __shfl_xor(snd, 1);
    cvtot = ((m16 & 1) ? rs3[1] : rs3[0]) + rcv;
  }
  // lane m16 holds cv[r=m16>>2][c=m16&3]; lane d wants channel d/3
  const int d3 = (m16 < 12) ? ((m16 * 11) >> 5) : 3;
  float tr[4];
#pragma unroll
  for (int r = 0; r < 4; ++r) {
    float cvv = __shfl(cvtot, (quad << 4) + r * 4 + d3);
    tr[r] = (m16 < 12) ? bf2f(sCD[16 * wv + quad * 4 + r][m16]) * cvv : 0.f;
  }

  // ---- per-wave segment reduce over this wave's 16 slots + atomics ----
  int s = 0;
  while (s < 16) {
    int n = (int)(sRC[16 * wv + s] >> 16);        // uniform (broadcast)
    int e2 = s + 1;
    while (e2 < 16 && (int)(sRC[16 * wv + e2] >> 16) == n) ++e2;
    float hp0 = 0.f, hp1 = 0.f, hp2 = 0.f, hp3 = 0.f, lp = 0.f, cp = 0.f;
#pragma unroll
    for (int r = 0; r < 4; ++r) {
      int rowi = quad * 4 + r;
      float w = (rowi >= s && rowi < e2) ? ex[r] : 0.f;
      hp0 += w * acc[4][r];
      hp1 += w * acc[5][r];
      hp2 += w * acc[6][r];
      hp3 += w * acc[7][r];
      lp  += (rowi >= s && rowi < e2) ? ex[r] : 0.f;
      cp  += w * tr[r];
    }
    hp0 += __shfl_xor(hp0, 16); hp0 += __shfl_xor(hp0, 32);
    hp1 += __shfl_xor(hp1, 16); hp1 += __shfl_xor(hp1, 32);
    hp2 += __shfl_xor(hp2, 16); hp2 += __shfl_xor(hp2, 32);
    hp3 += __shfl_xor(hp3, 16); hp3 += __shfl_xor(hp3, 32);
    lp  += __shfl_xor(lp, 16);  lp  += __shfl_xor(lp, 32);
    cp  += __shfl_xor(cp, 16);  cp  += __shfl_xor(cp, 32);
    if (quad == 0) {
      float* hg = hacc_g + (size_t)n * 64;
      atomicAdd(hg + m16,      hp0);
      atomicAdd(hg + m16 + 16, hp1);
      atomicAdd(hg + m16 + 32, hp2);
      atomicAdd(hg + m16 + 48, hp3);
      if (m16 < 12) atomicAdd(cacc_g + (size_t)n * 12 + m16, cp);
      if (m16 == 0) atomicAdd(l_g + n, lp);
    }
    s = e2;
  }
}

// ---------------- finalize ----------------
__global__ __launch_bounds__(256)
void k_fin(const float* __restrict__ h, const float* __restrict__ coord,
           const int* __restrict__ row, const int* __restrict__ iperm,
           const float* __restrict__ exg, const float* __restrict__ l_g,
           const float* __restrict__ hacc_g, const float* __restrict__ cacc_g,
           float* __restrict__ out) {
  const int wv = threadIdx.x >> 6, lane = threadIdx.x & 63;
  const int node = blockIdx.x * 4 + wv;
  const float l = l_g[node];
  const float inv = (l > 0.f) ? 1.f / l : 0.f;
  out[node * 64 + lane] =
      h[(size_t)node * 64 + lane] + hacc_g[(size_t)node * 64 + lane] * inv;
  if (lane < 12)
    out[NN * 64 + node * 12 + lane] =
        coord[node * 12 + lane] + cacc_g[(size_t)node * 12 + lane] * inv;
  const int e = blockIdx.x * 256 + threadIdx.x;   // grid covers 3.2M >= NE
  if (e < NE) {
    float le = l_g[row[e]];                       // node with an edge: le > 0
    out[NN * 64 + NN * 12 + e] = exg[iperm[e]] * __builtin_amdgcn_rcpf(le);
  }
}

extern "C" void kernel_launch(void* const* d_in, const int* in_sizes, int n_in,
                              void* d_out, int out_size, void* d_ws, size_t ws_size,
                              hipStream_t stream) {
  const float* h         = (const float*)d_in[0];
  const float* coord     = (const float*)d_in[1];
  const int*   row       = (const int*)d_in[2];
  const int*   col       = (const int*)d_in[3];
  const float* edge_attr = (const float*)d_in[4];
  const float* Wq        = (const float*)d_in[5];
  const float* bq        = (const float*)d_in[6];
  const float* Wkv       = (const float*)d_in[7];
  const float* bkv       = (const float*)d_in[8];
  const float* W1        = (const float*)d_in[9];
  const float* b1        = (const float*)d_in[10];
  const float* W2        = (const float*)d_in[11];
  float* out = (float*)d_out;

  size_t off = 0;
  char* wsb = (char*)d_ws;
  auto alloc = [&](size_t bytes) {
    off = (off + 255) & ~(size_t)255;
    void* p = wsb + off; off += bytes; return p;
  };
  // ---- zeroed region (contiguous, one memset) ----
  int*            deg      = (int*)alloc((size_t)NN * 4);
  float*          l_g      = (float*)alloc((size_t)NN * 4);
  float*          hacc_g   = (float*)alloc((size_t)NN * 64 * 4);
  float*          cacc_g   = (float*)alloc((size_t)NN * 12 * 4);
  size_t zbytes = off;
  // ---- rest ----
  float*          norm_part= (float*)alloc((size_t)NPREB * 16 * 4);
  float*          rnorm    = (float*)alloc(16 * 4);
  int*            startA   = (int*)alloc(((size_t)NN + 1) * 4);
  int*            cursor   = (int*)alloc((size_t)NN * 4);
  int*            iperm    = (int*)alloc((size_t)NE * 4);
  float*          exg      = (float*)alloc((size_t)NE * 4);
  uint4*          rec      = (uint4*)alloc((size_t)NE * 64);
  uint4*          eab      = (uint4*)alloc((size_t)NE * 32);
  unsigned short* qg2      = (unsigned short*)alloc((size_t)NN * 64 * 2);
  unsigned short* hb       = (unsigned short*)alloc((size_t)NN * 64 * 2);
  unsigned short* Bkvb     = (unsigned short*)alloc(128 * 104 * 2);
  unsigned short* W1tb     = (unsigned short*)alloc(64 * 88 * 2);
  unsigned*       Wqp      = (unsigned*)alloc(32 * 64 * 4);

  hipMemsetAsync(d_ws, 0, zbytes, stream);

  k_pre<<<NPREB, 256, 0, stream>>>(coord, row, col, Wkv, W1, Wq,
                                   norm_part, deg, Bkvb, W1tb, Wqp);
  k_scanq<<<1 + NN / 16, 1024, 0, stream>>>(deg, startA, cursor, norm_part,
                                            rnorm, h, Wqp, bq, qg2, hb);
  k_scatter<<<(NE + 255) / 256, 256, 0, stream>>>(row, col, edge_attr, coord,
                                                  rnorm, cursor, iperm, rec, eab);
  k_kv<<<NE / 128, 512, 0, stream>>>(hb, rec, eab, bkv, b1, W2,
                                     Bkvb, W1tb, qg2,
                                     exg, l_g, hacc_g, cacc_g);
  k_fin<<<NN / 4, 256, 0, stream>>>(h, coord, row, iperm, exg, l_g,
                                    hacc_g, cacc_g, out);
}

// Round 8
// 497.644 us; speedup vs baseline: 1.0209x; 1.0209x over previous
//
#include <hip/hip_runtime.h>
#include <math.h>

#define NN 50000
#define NE 800000
#define NPREB 2048   // k_pre grid (blocks); norm_part rows

typedef __attribute__((ext_vector_type(8))) short short8;
typedef __attribute__((ext_vector_type(4))) float floatx4;

__device__ __forceinline__ unsigned short bf16_of(float x) {
  unsigned u = __float_as_uint(x);
  u += 0x7fffu + ((u >> 16) & 1u);
  return (unsigned short)(u >> 16);
}
__device__ __forceinline__ float bf2f(unsigned short u) {
  return __uint_as_float(((unsigned)u) << 16);
}
__device__ __forceinline__ unsigned pack_bf(float a, float b) {
  unsigned ua = __float_as_uint(a); ua += 0x7fffu + ((ua >> 16) & 1u);
  unsigned ub = __float_as_uint(b); ub += 0x7fffu + ((ub >> 16) & 1u);
  return (ua >> 16) | (ub & 0xffff0000u);
}
__device__ __forceinline__ float blo(unsigned w) { return __uint_as_float(w << 16); }
__device__ __forceinline__ float bhi(unsigned w) { return __uint_as_float(w & 0xffff0000u); }

// ---------- k_pre: weights + radial-norm partials + degree + edge record ----
// The edge loop ALREADY gathers coord and computes rad for the norm — now it
// also emits a 96B original-order record per edge (coalesced):
//   uint 0..15 : rad fp32 (un-normalized)
//   uint 16..21: cd bf16 pairs
//   uint 22    : row<<16|col     uint 23: pad
// k_scatter then permutes records without re-gathering (R7's +39us mistake).
__global__ __launch_bounds__(256)
void k_pre(const float* __restrict__ coord, const int* __restrict__ row,
           const int* __restrict__ col, const float* __restrict__ Wkv,
           const float* __restrict__ W1, const float* __restrict__ Wq,
           float* __restrict__ norm_part, int* __restrict__ deg,
           unsigned* __restrict__ erec,
           unsigned short* __restrict__ Bkvb, unsigned short* __restrict__ W1tb,
           unsigned* __restrict__ Wqp) {
  __shared__ float nred[4][16];
  const int gid = blockIdx.x * 256 + threadIdx.x;
  const int np = gridDim.x * 256;
  for (int idx = gid; idx < 128 * 96; idx += np) {
    int n = idx & 127, kk = idx >> 7;
    float w = (n < 64) ? Wkv[kk * 128 + 2 * n] : Wkv[kk * 128 + 2 * (n - 64) + 1];
    Bkvb[n * 104 + kk] = bf16_of(w);
  }
  for (int idx = gid; idx < 64 * 64; idx += np) {
    int n = idx & 63, kk = idx >> 6;
    W1tb[n * 88 + kk] = bf16_of(W1[kk * 64 + n]);
  }
  for (int idx = gid; idx < 32 * 64; idx += np) {
    int i2 = idx >> 6, j = idx & 63;
    Wqp[idx] = pack_bf(Wq[(2 * i2) * 64 + j], Wq[(2 * i2 + 1) * 64 + j]);
  }
  const int lane = threadIdx.x & 63;
  const int grp = lane >> 4, g = lane & 15;
  const int c4 = g >> 2, f4 = g & 3;
  const int wid = blockIdx.x * 4 + (threadIdx.x >> 6);
  const int nw = gridDim.x * 4;
  float acc = 0.f;
  for (int base = wid * 4; base < NE; base += nw * 4) {
    int e = base + grp;
    int r = row[e], c = col[e];
    float cd = 0.f;
    if (g < 12) cd = coord[r * 12 + g] - coord[c * 12 + g];
    float rad = 0.f;
#pragma unroll
    for (int d = 0; d < 3; ++d)
      rad += __shfl(cd, grp * 16 + c4 * 3 + d) * __shfl(cd, grp * 16 + f4 * 3 + d);
    acc += rad * rad;
    // emit record
    unsigned eb = (unsigned)e * 24u;
    erec[eb + g] = __float_as_uint(rad);
    float cdn = __shfl(cd, grp * 16 + g + 1);
    if (!(g & 1) && g < 12) erec[eb + 16 + (g >> 1)] = pack_bf(cd, cdn);
    if (g == 15) erec[eb + 22] = ((unsigned)r << 16) | (unsigned)c;
    if (g == 0) atomicAdd(deg + r, 1);
  }
  acc += __shfl_xor(acc, 16);
  acc += __shfl_xor(acc, 32);
  if (lane < 16) nred[threadIdx.x >> 6][lane] = acc;
  __syncthreads();
  if (threadIdx.x < 16) {
    float s = nred[0][threadIdx.x] + nred[1][threadIdx.x] +
              nred[2][threadIdx.x] + nred[3][threadIdx.x];
    norm_part[blockIdx.x * 16 + threadIdx.x] = s;
  }
}

// ---------- k_scanq: block 0 = norm reduce + CSR scan; blocks >=1 = q/hb ----------
__global__ __launch_bounds__(1024)
void k_scanq(const int* __restrict__ deg, int* __restrict__ startA,
             int* __restrict__ cursor, const float* __restrict__ norm_part,
             float* __restrict__ rnorm, const float* __restrict__ h,
             const unsigned* __restrict__ Wqp, const float* __restrict__ bq,
             unsigned short* __restrict__ qg2, unsigned short* __restrict__ hb) {
  __shared__ int part[1024];
  __shared__ float nr[64][16];
  __shared__ unsigned sWqp[32 * 64];
  __shared__ float sHr[16][64];
  const int t = threadIdx.x;
  if (blockIdx.x == 0) {
    {  // reduce norm_part[NPREB][16] -> rnorm[16], no atomics
      const int i = t >> 4, c = t & 15;
      float s = 0.f;
#pragma unroll
      for (int j = 0; j < NPREB / 64; ++j) s += norm_part[((i + 64 * j) << 4) + c];
      nr[i][c] = s;
    }
    __syncthreads();
    if (t < 16) {
      float s = 0.f;
#pragma unroll 8
      for (int i = 0; i < 64; ++i) s += nr[i][t];
      rnorm[t] = 1.0f / fmaxf(sqrtf(s), 1e-12f);
    }
    const int CH = (NN + 1023) / 1024;
    const int lo = t * CH, hi = (lo + CH < NN) ? lo + CH : NN;
    int s = 0;
    for (int i = lo; i < hi; ++i) s += deg[i];
    part[t] = s;
    __syncthreads();
    for (int off = 1; off < 1024; off <<= 1) {
      int v = (t >= off) ? part[t - off] : 0;
      __syncthreads();
      part[t] += v;
      __syncthreads();
    }
    int base = (t == 0) ? 0 : part[t - 1];
    for (int i = lo; i < hi; ++i) {
      startA[i] = base; cursor[i] = base; base += deg[i];
    }
    if (t == 1023) startA[NN] = base;
    return;
  }
  for (int idx = t; idx < 2048; idx += 1024) sWqp[idx] = Wqp[idx];
  __syncthreads();
  const int wv = t >> 6, lane = t & 63;
  const int node = (blockIdx.x - 1) * 16 + wv;
  float hv = h[(size_t)node * 64 + lane];
  sHr[wv][lane] = hv;
  hb[(size_t)node * 64 + lane] = bf16_of(hv);
  float q = bq[lane];
  const float2* hp = (const float2*)sHr[wv];
#pragma unroll 8
  for (int i2 = 0; i2 < 32; ++i2) {
    unsigned w = sWqp[i2 * 64 + lane];
    float2 hbv = hp[i2];
    q += hbv.x * blo(w) + hbv.y * bhi(w);
  }
  qg2[(size_t)node * 64 + (lane & 15) * 4 + (lane >> 4)] = bf16_of(q);
}

// ---------- k_scatter: pure permuter (no gather, no einsum) ----------
// Reads the 96B original-order record coalesced, applies rad*rn -> bf16,
// scatters the 64B permuted record + 32B edge_attr bf16.
__global__ void k_scatter(const float* __restrict__ edge_attr,
                          const float* __restrict__ rnorm,
                          const unsigned* __restrict__ erec,
                          int* __restrict__ cursor, int* __restrict__ iperm,
                          uint4* __restrict__ rec, uint4* __restrict__ eab) {
  int e = blockIdx.x * 256 + threadIdx.x;
  if (e >= NE) return;
  const uint4* er = (const uint4*)(erec + (size_t)e * 24);
  uint4 e0 = er[0], e1 = er[1], e2 = er[2], e3 = er[3], e4 = er[4], e5 = er[5];
  int r = (int)(e5.z >> 16);
  int p = atomicAdd(cursor + r, 1);
  iperm[e] = p;   // coalesced; lets k_fin write att coalesced
  // edge_attr -> bf16, scatter 32B
  {
    const float4* ep = (const float4*)(edge_attr + (size_t)e * 16);
    float4 f0 = ep[0], f1 = ep[1], f2 = ep[2], f3 = ep[3];
    uint4 a, b;
    a.x = pack_bf(f0.x, f0.y); a.y = pack_bf(f0.z, f0.w);
    a.z = pack_bf(f1.x, f1.y); a.w = pack_bf(f1.z, f1.w);
    b.x = pack_bf(f2.x, f2.y); b.y = pack_bf(f2.z, f2.w);
    b.z = pack_bf(f3.x, f3.y); b.w = pack_bf(f3.z, f3.w);
    eab[(size_t)p * 2]     = a;
    eab[(size_t)p * 2 + 1] = b;
  }
  float rn[16];
  {
    const float4* rp = (const float4*)rnorm;
#pragma unroll
    for (int q = 0; q < 4; ++q) {
      float4 v = rp[q];
      rn[q * 4] = v.x; rn[q * 4 + 1] = v.y; rn[q * 4 + 2] = v.z; rn[q * 4 + 3] = v.w;
    }
  }
  uint4 q0, q1;
  q0.x = pack_bf(__uint_as_float(e0.x) * rn[0],  __uint_as_float(e0.y) * rn[1]);
  q0.y = pack_bf(__uint_as_float(e0.z) * rn[2],  __uint_as_float(e0.w) * rn[3]);
  q0.z = pack_bf(__uint_as_float(e1.x) * rn[4],  __uint_as_float(e1.y) * rn[5]);
  q0.w = pack_bf(__uint_as_float(e1.z) * rn[6],  __uint_as_float(e1.w) * rn[7]);
  q1.x = pack_bf(__uint_as_float(e2.x) * rn[8],  __uint_as_float(e2.y) * rn[9]);
  q1.y = pack_bf(__uint_as_float(e2.z) * rn[10], __uint_as_float(e2.w) * rn[11]);
  q1.z = pack_bf(__uint_as_float(e3.x) * rn[12], __uint_as_float(e3.y) * rn[13]);
  q1.w = pack_bf(__uint_as_float(e3.z) * rn[14], __uint_as_float(e3.w) * rn[15]);
  uint4* rp4 = rec + (size_t)p * 4;
  rp4[0] = q0; rp4[1] = q1; rp4[2] = e4; rp4[3] = e5;  // e4/e5 = cd pairs, rc, pad
}

// -------- main fused kernel (unchanged from R7's verified 122.8us) --------
__global__ __launch_bounds__(512, 6)
void k_kv(const unsigned short* __restrict__ hb,
          const uint4* __restrict__ rec, const uint4* __restrict__ eab,
          const float* __restrict__ bkv, const float* __restrict__ b1,
          const float* __restrict__ W2,
          const unsigned short* __restrict__ Bkvb,
          const unsigned short* __restrict__ W1tb,
          const unsigned short* __restrict__ qg2,
          float* __restrict__ exg, float* __restrict__ l_g,
          float* __restrict__ hacc_g, float* __restrict__ cacc_g) {
  __shared__ __align__(16) unsigned short sA[128][104];   // rad|h|ea bf16; later v
  __shared__ __align__(16) unsigned short sB[128][104];   // [k|v]^T; later W1^T + cd
  __shared__ unsigned sRC[128];                           // row<<16 | col
  unsigned short (*sW1t)[88] = (unsigned short (*)[88])&sB[0][0];
  unsigned short (*sCD)[16] =
      (unsigned short (*)[16])((char*)&sB[0][0] + 64 * 88 * 2);  // 4KB in sB tail

  const int tid = threadIdx.x;
  const int base = blockIdx.x * 128;

  // prefetch W1^T (11,264 B) into registers; parked into sB's space post-GEMM1
  const uint4* gw = (const uint4*)W1tb;
  uint4 w1a = gw[tid];                 // 704 uint4 total; tid<512 all valid
  uint4 w1b;
  if (tid < 192) w1b = gw[512 + tid];

  // record staging: 1 coalesced uint4/thread (512 = 128 records x 4)
  uint4 rw = rec[(size_t)base * 4 + tid];
  const int rs = tid >> 2, rj = tid & 3;
  if (rj == 0)      *(uint4*)&sA[rs][0] = rw;    // rad*rn cols 0..7
  else if (rj == 1) *(uint4*)&sA[rs][8] = rw;    // rad*rn cols 8..15
  else if (rj == 3) sRC[rs] = rw.z;              // row|col (keeps rw.x/.y = cd 8..11)
  // rj==2 keeps rw = cd cols 0..7 in regs until the overlay barrier

  if (tid < 256) {                               // edge_attr bf16, coalesced
    int s = tid >> 1;
    *(uint4*)&sA[s][80 + (tid & 1) * 8] = eab[(size_t)base * 2 + tid];
  }
  {
    const uint4* gb = (const uint4*)Bkvb;
    uint4* sb = (uint4*)&sB[0][0];
    for (int idx = tid; idx < 1664; idx += 512) sb[idx] = gb[idx];
  }
  __syncthreads();   // sRC + sA(rad,ea) + sB visible

  for (int idx = tid; idx < 1024; idx += 512) {
    int s = idx >> 3, k8 = idx & 7;
    unsigned c = sRC[s] & 0xffffu;
    uint4 u = ((const uint4*)(hb + (size_t)c * 64))[k8];
    *(uint4*)&sA[s][16 + k8 * 8] = u;
  }
  __syncthreads();   // sA complete

  const int wv = tid >> 6, lane = tid & 63;
  const int m16 = lane & 15, quad = lane >> 4;
  const int arow = 16 * wv + m16;

  // kv = feat @ [Wk|Wv]
  floatx4 acc[8];
#pragma unroll
  for (int i = 0; i < 8; ++i) acc[i] = (floatx4){0.f, 0.f, 0.f, 0.f};
#pragma unroll
  for (int ks = 0; ks < 3; ++ks) {
    short8 af = *(const short8*)&sA[arow][ks * 32 + quad * 8];
#pragma unroll
    for (int nt = 0; nt < 8; ++nt) {
      short8 bf = *(const short8*)&sB[nt * 16 + m16][ks * 32 + quad * 8];
      acc[nt] = __builtin_amdgcn_mfma_f32_16x16x32_bf16(af, bf, acc[nt], 0, 0, 0);
    }
  }
#pragma unroll
  for (int nt = 0; nt < 4; ++nt) {
    float bk = bkv[2 * (m16 + 16 * nt)];
    float bv = bkv[2 * (m16 + 16 * nt) + 1];
#pragma unroll
    for (int r = 0; r < 4; ++r) { acc[nt][r] += bk; acc[nt + 4][r] += bv; }
  }
  // alpha = q . k -> ex = exp(alpha)   (no max stabilizer: |alpha| << 88)
  float part[4] = {0.f, 0.f, 0.f, 0.f};
#pragma unroll
  for (int r = 0; r < 4; ++r) {
    unsigned nrow = sRC[16 * wv + quad * 4 + r] >> 16;
    uint2 qp = *(const uint2*)(qg2 + (size_t)nrow * 64 + m16 * 4);
    part[r] += blo(qp.x) * acc[0][r] + bhi(qp.x) * acc[1][r] +
               blo(qp.y) * acc[2][r] + bhi(qp.y) * acc[3][r];
  }
#pragma unroll
  for (int off = 1; off < 16; off <<= 1) {
#pragma unroll
    for (int r = 0; r < 4; ++r) part[r] += __shfl_xor(part[r], off);
  }
  float ex[4];
#pragma unroll
  for (int r = 0; r < 4; ++r) ex[r] = __expf(part[r]);
  if (m16 == 0) {
#pragma unroll
    for (int r = 0; r < 4; ++r)
      exg[base + 16 * wv + quad * 4 + r] = ex[r];
  }
  // v (bf16) -> sA rows (wave-private) for the W1 GEMM; keep fp32 v in acc[4..7]
#pragma unroll
  for (int nt = 0; nt < 4; ++nt)
#pragma unroll
    for (int r = 0; r < 4; ++r)
      sA[16 * wv + quad * 4 + r][m16 + 16 * nt] = bf16_of(acc[4 + nt][r]);

  __syncthreads();   // all waves done reading sB (GEMM1)
  {                  // overlay W1^T into sB from regs; park cd into sB tail
    unsigned short* sw = &sB[0][0];
    *(uint4*)&sw[(size_t)tid * 8] = w1a;
    if (tid < 192) *(uint4*)&sw[(size_t)(512 + tid) * 8] = w1b;
    if (rj == 2) *(uint4*)&sCD[rs][0] = rw;        // cd cols 0..7
    else if (rj == 3) {
      uint2 t2; t2.x = rw.x; t2.y = rw.y;
      *(uint2*)&sCD[rs][8] = t2;                   // cd cols 8..11
    }
  }
  __syncthreads();   // sW1t + sCD visible

  // t = silu(v @ W1 + b1)
  floatx4 tacc[4];
#pragma unroll
  for (int i = 0; i < 4; ++i) tacc[i] = (floatx4){0.f, 0.f, 0.f, 0.f};
#pragma unroll
  for (int ks = 0; ks < 2; ++ks) {
    short8 af = *(const short8*)&sA[arow][ks * 32 + quad * 8];
#pragma unroll
    for (int nt = 0; nt < 4; ++nt) {
      short8 bf = *(const short8*)&sW1t[nt * 16 + m16][ks * 32 + quad * 8];
      tacc[nt] = __builtin_amdgcn_mfma_f32_16x16x32_bf16(af, bf, tacc[nt], 0, 0, 0);
    }
  }
#pragma unroll
  for (int nt = 0; nt < 4; ++nt) {
    float bb = b1[m16 + 16 * nt];
#pragma unroll
    for (int r = 0; r < 4; ++r) {
      float t = tacc[nt][r] + bb;
      tacc[nt][r] = t * __builtin_amdgcn_rcpf(1.f + __expf(-t));  // silu, rcp
    }
  }
  // cv = t @ W2 : local partials, then 16-lane REDUCE-SCATTER (15 shfl)
  float w0[16];   // j = r*4+c
#pragma unroll
  for (int r = 0; r < 4; ++r)
#pragma unroll
    for (int c = 0; c < 4; ++c) w0[r * 4 + c] = 0.f;
#pragma unroll
  for (int nt = 0; nt < 4; ++nt) {
    float4 w2r = ((const float4*)W2)[m16 + 16 * nt];
#pragma unroll
    for (int r = 0; r < 4; ++r) {
      w0[r * 4 + 0] += tacc[nt][r] * w2r.x;
      w0[r * 4 + 1] += tacc[nt][r] * w2r.y;
      w0[r * 4 + 2] += tacc[nt][r] * w2r.z;
      w0[r * 4 + 3] += tacc[nt][r] * w2r.w;
    }
  }
  float rs1[8];
#pragma unroll
  for (int jj = 0; jj < 8; ++jj) {
    float snd = (m16 & 8) ? w0[jj] : w0[jj + 8];
    float rcv = __shfl_xor(snd, 8);
    rs1[jj] = ((m16 & 8) ? w0[jj + 8] : w0[jj]) + rcv;
  }
  float rs2[4];
#pragma unroll
  for (int jj = 0; jj < 4; ++jj) {
    float snd = (m16 & 4) ? rs1[jj] : rs1[jj + 4];
    float rcv = __shfl_xor(snd, 4);
    rs2[jj] = ((m16 & 4) ? rs1[jj + 4] : rs1[jj]) + rcv;
  }
  float rs3[2];
#pragma unroll
  for (int jj = 0; jj < 2; ++jj) {
    float snd = (m16 & 2) ? rs2[jj] : rs2[jj + 2];
    float rcv = __shfl_xor(snd, 2);
    rs3[jj] = ((m16 & 2) ? rs2[jj + 2] : rs2[jj]) + rcv;
  }
  float cvtot;
  {
    float snd = (m16 & 1) ? rs3[0] : rs3[1];
    float rcv = __shfl_xor(snd, 1);
    cvtot = ((m16 & 1) ? rs3[1] : rs3[0]) + rcv;
  }
  // lane m16 holds cv[r=m16>>2][c=m16&3]; lane d wants channel d/3
  const int d3 = (m16 < 12) ? ((m16 * 11) >> 5) : 3;
  float tr[4];
#pragma unroll
  for (int r = 0; r < 4; ++r) {
    float cvv = __shfl(cvtot, (quad << 4) + r * 4 + d3);
    tr[r] = (m16 < 12) ? bf2f(sCD[16 * wv + quad * 4 + r][m16]) * cvv : 0.f;
  }

  // ---- per-wave segment reduce over this wave's 16 slots + atomics ----
  int s = 0;
  while (s < 16) {
    int n = (int)(sRC[16 * wv + s] >> 16);        // uniform (broadcast)
    int e2 = s + 1;
    while (e2 < 16 && (int)(sRC[16 * wv + e2] >> 16) == n) ++e2;
    float hp0 = 0.f, hp1 = 0.f, hp2 = 0.f, hp3 = 0.f, lp = 0.f, cp = 0.f;
#pragma unroll
    for (int r = 0; r < 4; ++r) {
      int rowi = quad * 4 + r;
      float w = (rowi >= s && rowi < e2) ? ex[r] : 0.f;
      hp0 += w * acc[4][r];
      hp1 += w * acc[5][r];
      hp2 += w * acc[6][r];
      hp3 += w * acc[7][r];
      lp  += (rowi >= s && rowi < e2) ? ex[r] : 0.f;
      cp  += w * tr[r];
    }
    hp0 += __shfl_xor(hp0, 16); hp0 += __shfl_xor(hp0, 32);
    hp1 += __shfl_xor(hp1, 16); hp1 += __shfl_xor(hp1, 32);
    hp2 += __shfl_xor(hp2, 16); hp2 += __shfl_xor(hp2, 32);
    hp3 += __shfl_xor(hp3, 16); hp3 += __shfl_xor(hp3, 32);
    lp  += __shfl_xor(lp, 16);  lp  += __shfl_xor(lp, 32);
    cp  += __shfl_xor(cp, 16);  cp  += __shfl_xor(cp, 32);
    if (quad == 0) {
      float* hg = hacc_g + (size_t)n * 64;
      atomicAdd(hg + m16,      hp0);
      atomicAdd(hg + m16 + 16, hp1);
      atomicAdd(hg + m16 + 32, hp2);
      atomicAdd(hg + m16 + 48, hp3);
      if (m16 < 12) atomicAdd(cacc_g + (size_t)n * 12 + m16, cp);
      if (m16 == 0) atomicAdd(l_g + n, lp);
    }
    s = e2;
  }
}

// ---------------- finalize ----------------
__global__ __launch_bounds__(256)
void k_fin(const float* __restrict__ h, const float* __restrict__ coord,
           const int* __restrict__ row, const int* __restrict__ iperm,
           const float* __restrict__ exg, const float* __restrict__ l_g,
           const float* __restrict__ hacc_g, const float* __restrict__ cacc_g,
           float* __restrict__ out) {
  const int wv = threadIdx.x >> 6, lane = threadIdx.x & 63;
  const int node = blockIdx.x * 4 + wv;
  const float l = l_g[node];
  const float inv = (l > 0.f) ? 1.f / l : 0.f;
  out[node * 64 + lane] =
      h[(size_t)node * 64 + lane] + hacc_g[(size_t)node * 64 + lane] * inv;
  if (lane < 12)
    out[NN * 64 + node * 12 + lane] =
        coord[node * 12 + lane] + cacc_g[(size_t)node * 12 + lane] * inv;
  const int e = blockIdx.x * 256 + threadIdx.x;   // grid covers 3.2M >= NE
  if (e < NE) {
    float le = l_g[row[e]];                       // node with an edge: le > 0
    out[NN * 64 + NN * 12 + e] = exg[iperm[e]] * __builtin_amdgcn_rcpf(le);
  }
}

extern "C" void kernel_launch(void* const* d_in, const int* in_sizes, int n_in,
                              void* d_out, int out_size, void* d_ws, size_t ws_size,
                              hipStream_t stream) {
  const float* h         = (const float*)d_in[0];
  const float* coord     = (const float*)d_in[1];
  const int*   row       = (const int*)d_in[2];
  const int*   col       = (const int*)d_in[3];
  const float* edge_attr = (const float*)d_in[4];
  const float* Wq        = (const float*)d_in[5];
  const float* bq        = (const float*)d_in[6];
  const float* Wkv       = (const float*)d_in[7];
  const float* bkv       = (const float*)d_in[8];
  const float* W1        = (const float*)d_in[9];
  const float* b1        = (const float*)d_in[10];
  const float* W2        = (const float*)d_in[11];
  float* out = (float*)d_out;

  size_t off = 0;
  char* wsb = (char*)d_ws;
  auto alloc = [&](size_t bytes) {
    off = (off + 255) & ~(size_t)255;
    void* p = wsb + off; off += bytes; return p;
  };
  // ---- zeroed region (contiguous, one memset) ----
  int*            deg      = (int*)alloc((size_t)NN * 4);
  float*          l_g      = (float*)alloc((size_t)NN * 4);
  float*          hacc_g   = (float*)alloc((size_t)NN * 64 * 4);
  float*          cacc_g   = (float*)alloc((size_t)NN * 12 * 4);
  size_t zbytes = off;
  // ---- rest ----
  float*          norm_part= (float*)alloc((size_t)NPREB * 16 * 4);
  float*          rnorm    = (float*)alloc(16 * 4);
  int*            startA   = (int*)alloc(((size_t)NN + 1) * 4);
  int*            cursor   = (int*)alloc((size_t)NN * 4);
  int*            iperm    = (int*)alloc((size_t)NE * 4);
  float*          exg      = (float*)alloc((size_t)NE * 4);
  unsigned*       erec     = (unsigned*)alloc((size_t)NE * 96);
  uint4*          rec      = (uint4*)alloc((size_t)NE * 64);
  uint4*          eab      = (uint4*)alloc((size_t)NE * 32);
  unsigned short* qg2      = (unsigned short*)alloc((size_t)NN * 64 * 2);
  unsigned short* hb       = (unsigned short*)alloc((size_t)NN * 64 * 2);
  unsigned short* Bkvb     = (unsigned short*)alloc(128 * 104 * 2);
  unsigned short* W1tb     = (unsigned short*)alloc(64 * 88 * 2);
  unsigned*       Wqp      = (unsigned*)alloc(32 * 64 * 4);

  hipMemsetAsync(d_ws, 0, zbytes, stream);

  k_pre<<<NPREB, 256, 0, stream>>>(coord, row, col, Wkv, W1, Wq,
                                   norm_part, deg, erec, Bkvb, W1tb, Wqp);
  k_scanq<<<1 + NN / 16, 1024, 0, stream>>>(deg, startA, cursor, norm_part,
                                            rnorm, h, Wqp, bq, qg2, hb);
  k_scatter<<<(NE + 255) / 256, 256, 0, stream>>>(edge_attr, rnorm, erec,
                                                  cursor, iperm, rec, eab);
  k_kv<<<NE / 128, 512, 0, stream>>>(hb, rec, eab, bkv, b1, W2,
                                     Bkvb, W1tb, qg2,
                                     exg, l_g, hacc_g, cacc_g);
  k_fin<<<NN / 4, 256, 0, stream>>>(h, coord, row, iperm, exg, l_g,
                                    hacc_g, cacc_g, out);
}

// Round 9
// 482.728 us; speedup vs baseline: 1.0525x; 1.0309x over previous
//
#include <hip/hip_runtime.h>
#include <math.h>

#define NN 50000
#define NE 800000
#define NPREB 1024   // k_pre grid (blocks); norm_part rows

typedef __attribute__((ext_vector_type(8))) short short8;
typedef __attribute__((ext_vector_type(4))) float floatx4;

__device__ __forceinline__ unsigned short bf16_of(float x) {
  unsigned u = __float_as_uint(x);
  u += 0x7fffu + ((u >> 16) & 1u);
  return (unsigned short)(u >> 16);
}
__device__ __forceinline__ float bf2f(unsigned short u) {
  return __uint_as_float(((unsigned)u) << 16);
}
__device__ __forceinline__ unsigned pack_bf(float a, float b) {
  unsigned ua = __float_as_uint(a); ua += 0x7fffu + ((ua >> 16) & 1u);
  unsigned ub = __float_as_uint(b); ub += 0x7fffu + ((ub >> 16) & 1u);
  return (ua >> 16) | (ub & 0xffff0000u);
}
__device__ __forceinline__ float blo(unsigned w) { return __uint_as_float(w << 16); }
__device__ __forceinline__ float bhi(unsigned w) { return __uint_as_float(w & 0xffff0000u); }

// ---------- k_pre: weight conversion + radial-norm partials + degree count ----------
__global__ __launch_bounds__(256)
void k_pre(const float* __restrict__ coord, const int* __restrict__ row,
           const int* __restrict__ col, const float* __restrict__ Wkv,
           const float* __restrict__ W1, const float* __restrict__ Wq,
           float* __restrict__ norm_part, int* __restrict__ deg,
           unsigned short* __restrict__ Bkvb, unsigned short* __restrict__ W1tb,
           unsigned* __restrict__ Wqp) {
  __shared__ float nred[4][16];
  const int gid = blockIdx.x * 256 + threadIdx.x;
  const int np = gridDim.x * 256;
  for (int idx = gid; idx < 128 * 96; idx += np) {
    int n = idx & 127, kk = idx >> 7;
    float w = (n < 64) ? Wkv[kk * 128 + 2 * n] : Wkv[kk * 128 + 2 * (n - 64) + 1];
    Bkvb[n * 104 + kk] = bf16_of(w);
  }
  for (int idx = gid; idx < 64 * 64; idx += np) {
    int n = idx & 63, kk = idx >> 6;
    W1tb[n * 88 + kk] = bf16_of(W1[kk * 64 + n]);
  }
  for (int idx = gid; idx < 32 * 64; idx += np) {
    int i2 = idx >> 6, j = idx & 63;
    Wqp[idx] = pack_bf(Wq[(2 * i2) * 64 + j], Wq[(2 * i2 + 1) * 64 + j]);
  }
  const int lane = threadIdx.x & 63;
  const int grp = lane >> 4, g = lane & 15;
  const int c4 = g >> 2, f4 = g & 3;
  const int wid = blockIdx.x * 4 + (threadIdx.x >> 6);
  const int nw = gridDim.x * 4;
  float acc = 0.f;
  for (int base = wid * 4; base < NE; base += nw * 4) {
    int e = base + grp;
    int r = row[e], c = col[e];
    float cd = 0.f;
    if (g < 12) cd = coord[r * 12 + g] - coord[c * 12 + g];
    float rad = 0.f;
#pragma unroll
    for (int d = 0; d < 3; ++d)
      rad += __shfl(cd, grp * 16 + c4 * 3 + d) * __shfl(cd, grp * 16 + f4 * 3 + d);
    acc += rad * rad;
    if (g == 0) atomicAdd(deg + r, 1);
  }
  acc += __shfl_xor(acc, 16);
  acc += __shfl_xor(acc, 32);
  if (lane < 16) nred[threadIdx.x >> 6][lane] = acc;
  __syncthreads();
  if (threadIdx.x < 16) {
    float s = nred[0][threadIdx.x] + nred[1][threadIdx.x] +
              nred[2][threadIdx.x] + nred[3][threadIdx.x];
    norm_part[blockIdx.x * 16 + threadIdx.x] = s;
  }
}

// ---------- k_scanq: block 0 = norm reduce + CSR scan; blocks >=1 = q/hb ----------
__global__ __launch_bounds__(1024)
void k_scanq(const int* __restrict__ deg, int* __restrict__ startA,
             int* __restrict__ cursor, const float* __restrict__ norm_part,
             float* __restrict__ rnorm, const float* __restrict__ h,
             const unsigned* __restrict__ Wqp, const float* __restrict__ bq,
             unsigned short* __restrict__ qg2, unsigned short* __restrict__ hb) {
  __shared__ int part[1024];
  __shared__ float nr[64][16];
  __shared__ unsigned sWqp[32 * 64];
  __shared__ float sHr[16][64];
  const int t = threadIdx.x;
  if (blockIdx.x == 0) {
    {  // reduce norm_part[NPREB][16] -> rnorm[16], no atomics
      const int i = t >> 4, c = t & 15;
      float s = 0.f;
#pragma unroll
      for (int j = 0; j < NPREB / 64; ++j) s += norm_part[((i + 64 * j) << 4) + c];
      nr[i][c] = s;
    }
    __syncthreads();
    if (t < 16) {
      float s = 0.f;
#pragma unroll 8
      for (int i = 0; i < 64; ++i) s += nr[i][t];
      rnorm[t] = 1.0f / fmaxf(sqrtf(s), 1e-12f);
    }
    const int CH = (NN + 1023) / 1024;
    const int lo = t * CH, hi = (lo + CH < NN) ? lo + CH : NN;
    int s = 0;
    for (int i = lo; i < hi; ++i) s += deg[i];
    part[t] = s;
    __syncthreads();
    for (int off = 1; off < 1024; off <<= 1) {
      int v = (t >= off) ? part[t - off] : 0;
      __syncthreads();
      part[t] += v;
      __syncthreads();
    }
    int base = (t == 0) ? 0 : part[t - 1];
    for (int i = lo; i < hi; ++i) {
      startA[i] = base; cursor[i] = base; base += deg[i];
    }
    if (t == 1023) startA[NN] = base;
    return;
  }
  for (int idx = t; idx < 2048; idx += 1024) sWqp[idx] = Wqp[idx];
  __syncthreads();
  const int wv = t >> 6, lane = t & 63;
  const int node = (blockIdx.x - 1) * 16 + wv;
  float hv = h[(size_t)node * 64 + lane];
  sHr[wv][lane] = hv;
  hb[(size_t)node * 64 + lane] = bf16_of(hv);
  float q = bq[lane];
  const float2* hp = (const float2*)sHr[wv];
#pragma unroll 8
  for (int i2 = 0; i2 < 32; ++i2) {
    unsigned w = sWqp[i2 * 64 + lane];
    float2 hbv = hp[i2];
    q += hbv.x * blo(w) + hbv.y * bhi(w);
  }
  qg2[(size_t)node * 64 + (lane & 15) * 4 + (lane >> 4)] = bf16_of(q);
}

// ---------- k_scatter: producer-side permute of edge data (R6 form) ----------
__global__ void k_scatter(const int* __restrict__ row, const int* __restrict__ col,
                          const float* __restrict__ edge_attr,
                          int* __restrict__ cursor, int* __restrict__ iperm,
                          unsigned* __restrict__ rcp, uint4* __restrict__ eab) {
  int e = blockIdx.x * 256 + threadIdx.x;
  if (e < NE) {
    int r = row[e], c = col[e];
    int p = atomicAdd(cursor + r, 1);
    iperm[e] = p;   // coalesced; lets k_fin write att coalesced
    rcp[p] = ((unsigned)r << 16) | (unsigned)c;
    const float4* ep = (const float4*)(edge_attr + (size_t)e * 16);
    float4 f0 = ep[0], f1 = ep[1], f2 = ep[2], f3 = ep[3];
    uint4 a, b;
    a.x = pack_bf(f0.x, f0.y); a.y = pack_bf(f0.z, f0.w);
    a.z = pack_bf(f1.x, f1.y); a.w = pack_bf(f1.z, f1.w);
    b.x = pack_bf(f2.x, f2.y); b.y = pack_bf(f2.z, f2.w);
    b.z = pack_bf(f3.x, f3.y); b.w = pack_bf(f3.z, f3.w);
    eab[(size_t)p * 2]     = a;
    eab[(size_t)p * 2 + 1] = b;
  }
}

// -------- main fused kernel (R6 base, 486us total) + barrier-1 removal ------
// The hb-gather and phase-1 now read row|col DIRECTLY from rcp (uniform per
// 8-thread / 16-lane group -> broadcast-coalesced, L1-hot) instead of via LDS
// sRC. That removes the first __syncthreads entirely: the random hb gather
// issues at t=0 and its latency hides under sB staging + the radial einsum.
// sRC is still written for the post-GEMM phases (alpha, segment reduce).
__global__ __launch_bounds__(512, 6)
void k_kv(const unsigned short* __restrict__ hb, const float* __restrict__ coord,
          const float* __restrict__ bkv, const float* __restrict__ b1,
          const float* __restrict__ W2, const float* __restrict__ rnorm,
          const unsigned* __restrict__ rcp, const uint4* __restrict__ eab,
          const unsigned short* __restrict__ Bkvb,
          const unsigned short* __restrict__ W1tb,
          const unsigned short* __restrict__ qg2,
          float* __restrict__ exg, float* __restrict__ l_g,
          float* __restrict__ hacc_g, float* __restrict__ cacc_g) {
  __shared__ __align__(16) unsigned short sA[128][104];   // feat bf16; later v + cd
  __shared__ __align__(16) unsigned short sB[128][104];   // [k|v]^T bf16; later W1^T
  __shared__ unsigned sRC[128];                           // row<<16 | col
  unsigned short (*sW1t)[88] = (unsigned short (*)[88])&sB[0][0];

  const int tid = threadIdx.x;
  const int base = blockIdx.x * 128;

  // prefetch W1^T (11,264 B) into registers; parked into sB's space post-GEMM1
  const uint4* gw = (const uint4*)W1tb;
  uint4 w1a = gw[tid];                 // 704 uint4 total; tid<512 all valid
  uint4 w1b;
  if (tid < 192) w1b = gw[512 + tid];

  if (tid < 128) sRC[tid] = rcp[base + tid];        // for post-GEMM phases
  if (tid < 256) {                                  // edge_attr bf16, coalesced
    int s = tid >> 1;
    *(uint4*)&sA[s][80 + (tid & 1) * 8] = eab[(size_t)base * 2 + tid];
  }
  // hb gather starts immediately — col from rcp directly (8-way uniform)
  for (int idx = tid; idx < 1024; idx += 512) {
    int s = idx >> 3, k8 = idx & 7;
    unsigned c = rcp[base + s] & 0xffffu;
    uint4 u = ((const uint4*)(hb + (size_t)c * 64))[k8];
    *(uint4*)&sA[s][16 + k8 * 8] = u;
  }
  {
    const uint4* gb = (const uint4*)Bkvb;
    uint4* sb = (uint4*)&sB[0][0];
    for (int idx = tid; idx < 1664; idx += 512) sb[idx] = gb[idx];
  }
  const int wv = tid >> 6, lane = tid & 63;
  float cdp[4];   // this wave's coord_diff values, parked to LDS after GEMM1
  {
    const int grp = lane >> 4, g = lane & 15;
    const int c4 = g >> 2, f4 = g & 3;
    const float rn = rnorm[g];
#pragma unroll
    for (int it = 0; it < 4; ++it) {
      int slot = 16 * wv + it * 4 + grp;
      unsigned rc = rcp[base + slot];               // uniform per 16-lane group
      int r = (int)(rc >> 16), c = (int)(rc & 0xffffu);
      float cd = 0.f;
      if (g < 12) cd = coord[r * 12 + g] - coord[c * 12 + g];
      cdp[it] = cd;
      float rad = 0.f;
#pragma unroll
      for (int d = 0; d < 3; ++d)
        rad += __shfl(cd, grp * 16 + c4 * 3 + d) * __shfl(cd, grp * 16 + f4 * 3 + d);
      sA[slot][g] = bf16_of(rad * rn);
    }
  }
  __syncthreads();   // single staging barrier: sA + sB + sRC all visible

  const int m16 = lane & 15, quad = lane >> 4;
  const int arow = 16 * wv + m16;

  // kv = feat @ [Wk|Wv]
  floatx4 acc[8];
#pragma unroll
  for (int i = 0; i < 8; ++i) acc[i] = (floatx4){0.f, 0.f, 0.f, 0.f};
#pragma unroll
  for (int ks = 0; ks < 3; ++ks) {
    short8 af = *(const short8*)&sA[arow][ks * 32 + quad * 8];
#pragma unroll
    for (int nt = 0; nt < 8; ++nt) {
      short8 bf = *(const short8*)&sB[nt * 16 + m16][ks * 32 + quad * 8];
      acc[nt] = __builtin_amdgcn_mfma_f32_16x16x32_bf16(af, bf, acc[nt], 0, 0, 0);
    }
  }
#pragma unroll
  for (int nt = 0; nt < 4; ++nt) {
    float bk = bkv[2 * (m16 + 16 * nt)];
    float bv = bkv[2 * (m16 + 16 * nt) + 1];
#pragma unroll
    for (int r = 0; r < 4; ++r) { acc[nt][r] += bk; acc[nt + 4][r] += bv; }
  }
  // alpha = q . k -> ex = exp(alpha)   (no max stabilizer: |alpha| << 88)
  float part[4] = {0.f, 0.f, 0.f, 0.f};
#pragma unroll
  for (int r = 0; r < 4; ++r) {
    unsigned nrow = sRC[16 * wv + quad * 4 + r] >> 16;
    uint2 qp = *(const uint2*)(qg2 + (size_t)nrow * 64 + m16 * 4);
    part[r] += blo(qp.x) * acc[0][r] + bhi(qp.x) * acc[1][r] +
               blo(qp.y) * acc[2][r] + bhi(qp.y) * acc[3][r];
  }
#pragma unroll
  for (int off = 1; off < 16; off <<= 1) {
#pragma unroll
    for (int r = 0; r < 4; ++r) part[r] += __shfl_xor(part[r], off);
  }
  float ex[4];
#pragma unroll
  for (int r = 0; r < 4; ++r) ex[r] = __expf(part[r]);
  if (m16 == 0) {
#pragma unroll
    for (int r = 0; r < 4; ++r)
      exg[base + 16 * wv + quad * 4 + r] = ex[r];
  }
  // v (bf16) -> sA rows (wave-private) for the W1 GEMM; keep fp32 v in acc[4..7]
#pragma unroll
  for (int nt = 0; nt < 4; ++nt)
#pragma unroll
    for (int r = 0; r < 4; ++r)
      sA[16 * wv + quad * 4 + r][m16 + 16 * nt] = bf16_of(acc[4 + nt][r]);
  // park coord_diff in sA cols 64..75 (dead after this wave's own A-reads)
#pragma unroll
  for (int it = 0; it < 4; ++it)
    if (m16 < 12) sA[16 * wv + it * 4 + quad][64 + m16] = bf16_of(cdp[it]);

  __syncthreads();   // all waves done reading sB (GEMM1)
  {                  // overlay W1^T into sB's space from prefetched regs
    unsigned short* sw = &sB[0][0];
    *(uint4*)&sw[(size_t)tid * 8] = w1a;
    if (tid < 192) *(uint4*)&sw[(size_t)(512 + tid) * 8] = w1b;
  }
  __syncthreads();   // sW1t visible

  // t = silu(v @ W1 + b1)
  floatx4 tacc[4];
#pragma unroll
  for (int i = 0; i < 4; ++i) tacc[i] = (floatx4){0.f, 0.f, 0.f, 0.f};
#pragma unroll
  for (int ks = 0; ks < 2; ++ks) {
    short8 af = *(const short8*)&sA[arow][ks * 32 + quad * 8];
#pragma unroll
    for (int nt = 0; nt < 4; ++nt) {
      short8 bf = *(const short8*)&sW1t[nt * 16 + m16][ks * 32 + quad * 8];
      tacc[nt] = __builtin_amdgcn_mfma_f32_16x16x32_bf16(af, bf, tacc[nt], 0, 0, 0);
    }
  }
#pragma unroll
  for (int nt = 0; nt < 4; ++nt) {
    float bb = b1[m16 + 16 * nt];
#pragma unroll
    for (int r = 0; r < 4; ++r) {
      float t = tacc[nt][r] + bb;
      tacc[nt][r] = t * __builtin_amdgcn_rcpf(1.f + __expf(-t));  // silu, rcp
    }
  }
  // cv = t @ W2 : local partials, then 16-lane REDUCE-SCATTER (15 shfl)
  float w0[16];   // j = r*4+c
#pragma unroll
  for (int r = 0; r < 4; ++r)
#pragma unroll
    for (int c = 0; c < 4; ++c) w0[r * 4 + c] = 0.f;
#pragma unroll
  for (int nt = 0; nt < 4; ++nt) {
    float4 w2r = ((const float4*)W2)[m16 + 16 * nt];
#pragma unroll
    for (int r = 0; r < 4; ++r) {
      w0[r * 4 + 0] += tacc[nt][r] * w2r.x;
      w0[r * 4 + 1] += tacc[nt][r] * w2r.y;
      w0[r * 4 + 2] += tacc[nt][r] * w2r.z;
      w0[r * 4 + 3] += tacc[nt][r] * w2r.w;
    }
  }
  float rs1[8];
#pragma unroll
  for (int jj = 0; jj < 8; ++jj) {
    float snd = (m16 & 8) ? w0[jj] : w0[jj + 8];
    float rcv = __shfl_xor(snd, 8);
    rs1[jj] = ((m16 & 8) ? w0[jj + 8] : w0[jj]) + rcv;
  }
  float rs2[4];
#pragma unroll
  for (int jj = 0; jj < 4; ++jj) {
    float snd = (m16 & 4) ? rs1[jj] : rs1[jj + 4];
    float rcv = __shfl_xor(snd, 4);
    rs2[jj] = ((m16 & 4) ? rs1[jj + 4] : rs1[jj]) + rcv;
  }
  float rs3[2];
#pragma unroll
  for (int jj = 0; jj < 2; ++jj) {
    float snd = (m16 & 2) ? rs2[jj] : rs2[jj + 2];
    float rcv = __shfl_xor(snd, 2);
    rs3[jj] = ((m16 & 2) ? rs2[jj + 2] : rs2[jj]) + rcv;
  }
  float cvtot;
  {
    float snd = (m16 & 1) ? rs3[0] : rs3[1];
    float rcv = __shfl_xor(snd, 1);
    cvtot = ((m16 & 1) ? rs3[1] : rs3[0]) + rcv;
  }
  // lane m16 holds cv[r=m16>>2][c=m16&3]; lane d wants channel d/3
  const int d3 = (m16 < 12) ? ((m16 * 11) >> 5) : 3;
  float tr[4];
#pragma unroll
  for (int r = 0; r < 4; ++r) {
    float cvv = __shfl(cvtot, (quad << 4) + r * 4 + d3);
    tr[r] = (m16 < 12) ? bf2f(sA[16 * wv + quad * 4 + r][64 + m16]) * cvv : 0.f;
  }

  // ---- per-wave segment reduce over this wave's 16 slots + atomics ----
  int s = 0;
  while (s < 16) {
    int n = (int)(sRC[16 * wv + s] >> 16);        // uniform (broadcast)
    int e2 = s + 1;
    while (e2 < 16 && (int)(sRC[16 * wv + e2] >> 16) == n) ++e2;
    float hp0 = 0.f, hp1 = 0.f, hp2 = 0.f, hp3 = 0.f, lp = 0.f, cp = 0.f;
#pragma unroll
    for (int r = 0; r < 4; ++r) {
      int rowi = quad * 4 + r;
      float w = (rowi >= s && rowi < e2) ? ex[r] : 0.f;
      hp0 += w * acc[4][r];
      hp1 += w * acc[5][r];
      hp2 += w * acc[6][r];
      hp3 += w * acc[7][r];
      lp  += (rowi >= s && rowi < e2) ? ex[r] : 0.f;
      cp  += w * tr[r];
    }
    hp0 += __shfl_xor(hp0, 16); hp0 += __shfl_xor(hp0, 32);
    hp1 += __shfl_xor(hp1, 16); hp1 += __shfl_xor(hp1, 32);
    hp2 += __shfl_xor(hp2, 16); hp2 += __shfl_xor(hp2, 32);
    hp3 += __shfl_xor(hp3, 16); hp3 += __shfl_xor(hp3, 32);
    lp  += __shfl_xor(lp, 16);  lp  += __shfl_xor(lp, 32);
    cp  += __shfl_xor(cp, 16);  cp  += __shfl_xor(cp, 32);
    if (quad == 0) {
      float* hg = hacc_g + (size_t)n * 64;
      atomicAdd(hg + m16,      hp0);
      atomicAdd(hg + m16 + 16, hp1);
      atomicAdd(hg + m16 + 32, hp2);
      atomicAdd(hg + m16 + 48, hp3);
      if (m16 < 12) atomicAdd(cacc_g + (size_t)n * 12 + m16, cp);
      if (m16 == 0) atomicAdd(l_g + n, lp);
    }
    s = e2;
  }
}

// ---------------- finalize ----------------
__global__ __launch_bounds__(256)
void k_fin(const float* __restrict__ h, const float* __restrict__ coord,
           const int* __restrict__ row, const int* __restrict__ iperm,
           const float* __restrict__ exg, const float* __restrict__ l_g,
           const float* __restrict__ hacc_g, const float* __restrict__ cacc_g,
           float* __restrict__ out) {
  const int wv = threadIdx.x >> 6, lane = threadIdx.x & 63;
  const int node = blockIdx.x * 4 + wv;
  const float l = l_g[node];
  const float inv = (l > 0.f) ? 1.f / l : 0.f;
  out[node * 64 + lane] =
      h[(size_t)node * 64 + lane] + hacc_g[(size_t)node * 64 + lane] * inv;
  if (lane < 12)
    out[NN * 64 + node * 12 + lane] =
        coord[node * 12 + lane] + cacc_g[(size_t)node * 12 + lane] * inv;
  const int e = blockIdx.x * 256 + threadIdx.x;   // grid covers 3.2M >= NE
  if (e < NE) {
    float le = l_g[row[e]];                       // node with an edge: le > 0
    out[NN * 64 + NN * 12 + e] = exg[iperm[e]] * __builtin_amdgcn_rcpf(le);
  }
}

extern "C" void kernel_launch(void* const* d_in, const int* in_sizes, int n_in,
                              void* d_out, int out_size, void* d_ws, size_t ws_size,
                              hipStream_t stream) {
  const float* h         = (const float*)d_in[0];
  const float* coord     = (const float*)d_in[1];
  const int*   row       = (const int*)d_in[2];
  const int*   col       = (const int*)d_in[3];
  const float* edge_attr = (const float*)d_in[4];
  const float* Wq        = (const float*)d_in[5];
  const float* bq        = (const float*)d_in[6];
  const float* Wkv       = (const float*)d_in[7];
  const float* bkv       = (const float*)d_in[8];
  const float* W1        = (const float*)d_in[9];
  const float* b1        = (const float*)d_in[10];
  const float* W2        = (const float*)d_in[11];
  float* out = (float*)d_out;

  size_t off = 0;
  char* wsb = (char*)d_ws;
  auto alloc = [&](size_t bytes) {
    off = (off + 255) & ~(size_t)255;
    void* p = wsb + off; off += bytes; return p;
  };
  // ---- zeroed region (contiguous, one memset) ----
  int*            deg      = (int*)alloc((size_t)NN * 4);
  float*          l_g      = (float*)alloc((size_t)NN * 4);
  float*          hacc_g   = (float*)alloc((size_t)NN * 64 * 4);
  float*          cacc_g   = (float*)alloc((size_t)NN * 12 * 4);
  size_t zbytes = off;
  // ---- rest ----
  float*          norm_part= (float*)alloc((size_t)NPREB * 16 * 4);
  float*          rnorm    = (float*)alloc(16 * 4);
  int*            startA   = (int*)alloc(((size_t)NN + 1) * 4);
  int*            cursor   = (int*)alloc((size_t)NN * 4);
  unsigned*       rcp      = (unsigned*)alloc((size_t)NE * 4);
  int*            iperm    = (int*)alloc((size_t)NE * 4);
  float*          exg      = (float*)alloc((size_t)NE * 4);
  uint4*          eab      = (uint4*)alloc((size_t)NE * 32);
  unsigned short* qg2      = (unsigned short*)alloc((size_t)NN * 64 * 2);
  unsigned short* hb       = (unsigned short*)alloc((size_t)NN * 64 * 2);
  unsigned short* Bkvb     = (unsigned short*)alloc(128 * 104 * 2);
  unsigned short* W1tb     = (unsigned short*)alloc(64 * 88 * 2);
  unsigned*       Wqp      = (unsigned*)alloc(32 * 64 * 4);

  hipMemsetAsync(d_ws, 0, zbytes, stream);

  k_pre<<<NPREB, 256, 0, stream>>>(coord, row, col, Wkv, W1, Wq,
                                   norm_part, deg, Bkvb, W1tb, Wqp);
  k_scanq<<<1 + NN / 16, 1024, 0, stream>>>(deg, startA, cursor, norm_part,
                                            rnorm, h, Wqp, bq, qg2, hb);
  k_scatter<<<(NE + 255) / 256, 256, 0, stream>>>(row, col, edge_attr, cursor,
                                                  iperm, rcp, eab);
  k_kv<<<NE / 128, 512, 0, stream>>>(hb, coord, bkv, b1, W2, rnorm,
                                     rcp, eab, Bkvb, W1tb, qg2,
                                     exg, l_g, hacc_g, cacc_g);
  k_fin<<<NN / 4, 256, 0, stream>>>(h, coord, row, iperm, exg, l_g,
                                    hacc_g, cacc_g, out);
}

// Round 10
// 450.381 us; speedup vs baseline: 1.1281x; 1.0718x over previous
//
#include <hip/hip_runtime.h>
#include <math.h>

#define NN 50000
#define NE 800000
#define NPREB 1024   // k_pre grid (blocks); norm_part rows

typedef __attribute__((ext_vector_type(8))) short short8;
typedef __attribute__((ext_vector_type(4))) float floatx4;

__device__ __forceinline__ unsigned short bf16_of(float x) {
  unsigned u = __float_as_uint(x);
  u += 0x7fffu + ((u >> 16) & 1u);
  return (unsigned short)(u >> 16);
}
__device__ __forceinline__ float bf2f(unsigned short u) {
  return __uint_as_float(((unsigned)u) << 16);
}
__device__ __forceinline__ unsigned pack_bf(float a, float b) {
  unsigned ua = __float_as_uint(a); ua += 0x7fffu + ((ua >> 16) & 1u);
  unsigned ub = __float_as_uint(b); ub += 0x7fffu + ((ub >> 16) & 1u);
  return (ua >> 16) | (ub & 0xffff0000u);
}
__device__ __forceinline__ float blo(unsigned w) { return __uint_as_float(w << 16); }
__device__ __forceinline__ float bhi(unsigned w) { return __uint_as_float(w & 0xffff0000u); }

// ---------- k_pre: weight conversion + radial-norm partials + degree count ----------
__global__ __launch_bounds__(256)
void k_pre(const float* __restrict__ coord, const int* __restrict__ row,
           const int* __restrict__ col, const float* __restrict__ Wkv,
           const float* __restrict__ W1, const float* __restrict__ Wq,
           float* __restrict__ norm_part, int* __restrict__ deg,
           unsigned short* __restrict__ Bkvb, unsigned short* __restrict__ W1tb,
           unsigned* __restrict__ Wqp) {
  __shared__ float nred[4][16];
  const int gid = blockIdx.x * 256 + threadIdx.x;
  const int np = gridDim.x * 256;
  for (int idx = gid; idx < 128 * 96; idx += np) {
    int n = idx & 127, kk = idx >> 7;
    float w = (n < 64) ? Wkv[kk * 128 + 2 * n] : Wkv[kk * 128 + 2 * (n - 64) + 1];
    Bkvb[n * 104 + kk] = bf16_of(w);
  }
  for (int idx = gid; idx < 64 * 64; idx += np) {
    int n = idx & 63, kk = idx >> 6;
    W1tb[n * 88 + kk] = bf16_of(W1[kk * 64 + n]);
  }
  for (int idx = gid; idx < 32 * 64; idx += np) {
    int i2 = idx >> 6, j = idx & 63;
    Wqp[idx] = pack_bf(Wq[(2 * i2) * 64 + j], Wq[(2 * i2 + 1) * 64 + j]);
  }
  const int lane = threadIdx.x & 63;
  const int grp = lane >> 4, g = lane & 15;
  const int c4 = g >> 2, f4 = g & 3;
  const int wid = blockIdx.x * 4 + (threadIdx.x >> 6);
  const int nw = gridDim.x * 4;
  float acc = 0.f;
  for (int base = wid * 4; base < NE; base += nw * 4) {
    int e = base + grp;
    int r = row[e], c = col[e];
    float cd = 0.f;
    if (g < 12) cd = coord[r * 12 + g] - coord[c * 12 + g];
    float rad = 0.f;
#pragma unroll
    for (int d = 0; d < 3; ++d)
      rad += __shfl(cd, grp * 16 + c4 * 3 + d) * __shfl(cd, grp * 16 + f4 * 3 + d);
    acc += rad * rad;
    if (g == 0) atomicAdd(deg + r, 1);
  }
  acc += __shfl_xor(acc, 16);
  acc += __shfl_xor(acc, 32);
  if (lane < 16) nred[threadIdx.x >> 6][lane] = acc;
  __syncthreads();
  if (threadIdx.x < 16) {
    float s = nred[0][threadIdx.x] + nred[1][threadIdx.x] +
              nred[2][threadIdx.x] + nred[3][threadIdx.x];
    norm_part[blockIdx.x * 16 + threadIdx.x] = s;
  }
}

// ---------- k_scanq: block 0 = norm reduce + CSR scan; blocks >=1 = q/hb ----------
// Wqp now read DIRECT from global (8KB, L1-resident, coalesced) instead of
// LDS staging: halves the DS-pipe ops of the GEMV and removes a block barrier.
// startA dropped (dead since k_fin moved to iperm in R1).
__global__ __launch_bounds__(1024)
void k_scanq(const int* __restrict__ deg, int* __restrict__ cursor,
             const float* __restrict__ norm_part, float* __restrict__ rnorm,
             const float* __restrict__ h, const unsigned* __restrict__ Wqp,
             const float* __restrict__ bq,
             unsigned short* __restrict__ qg2, unsigned short* __restrict__ hb) {
  __shared__ int part[1024];
  __shared__ float nr[64][16];
  __shared__ float sHr[16][64];
  const int t = threadIdx.x;
  if (blockIdx.x == 0) {
    {  // reduce norm_part[NPREB][16] -> rnorm[16], no atomics
      const int i = t >> 4, c = t & 15;
      float s = 0.f;
#pragma unroll
      for (int j = 0; j < NPREB / 64; ++j) s += norm_part[((i + 64 * j) << 4) + c];
      nr[i][c] = s;
    }
    __syncthreads();
    if (t < 16) {
      float s = 0.f;
#pragma unroll 8
      for (int i = 0; i < 64; ++i) s += nr[i][t];
      rnorm[t] = 1.0f / fmaxf(sqrtf(s), 1e-12f);
    }
    const int CH = (NN + 1023) / 1024;
    const int lo = t * CH, hi = (lo + CH < NN) ? lo + CH : NN;
    int s = 0;
    for (int i = lo; i < hi; ++i) s += deg[i];
    part[t] = s;
    __syncthreads();
    for (int off = 1; off < 1024; off <<= 1) {
      int v = (t >= off) ? part[t - off] : 0;
      __syncthreads();
      part[t] += v;
      __syncthreads();
    }
    int base = (t == 0) ? 0 : part[t - 1];
    for (int i = lo; i < hi; ++i) {
      cursor[i] = base; base += deg[i];
    }
    return;
  }
  const int wv = t >> 6, lane = t & 63;
  const int node = (blockIdx.x - 1) * 16 + wv;
  float hv = h[(size_t)node * 64 + lane];
  sHr[wv][lane] = hv;   // same-wave write->read: lockstep, no barrier needed
  hb[(size_t)node * 64 + lane] = bf16_of(hv);
  float q = bq[lane];
  const float2* hp = (const float2*)sHr[wv];
#pragma unroll 8
  for (int i2 = 0; i2 < 32; ++i2) {
    unsigned w = Wqp[i2 * 64 + lane];   // global, L1-hot, coalesced
    float2 hbv = hp[i2];
    q += hbv.x * blo(w) + hbv.y * bhi(w);
  }
  qg2[(size_t)node * 64 + (lane & 15) * 4 + (lane >> 4)] = bf16_of(q);
}

// ---------- k_scatter: producer-side permute of edge data (R6 form) ----------
__global__ void k_scatter(const int* __restrict__ row, const int* __restrict__ col,
                          const float* __restrict__ edge_attr,
                          int* __restrict__ cursor, int* __restrict__ iperm,
                          unsigned* __restrict__ rcp, uint4* __restrict__ eab) {
  int e = blockIdx.x * 256 + threadIdx.x;
  if (e < NE) {
    int r = row[e], c = col[e];
    int p = atomicAdd(cursor + r, 1);
    iperm[e] = p;   // coalesced; lets k_fin write att coalesced
    rcp[p] = ((unsigned)r << 16) | (unsigned)c;
    const float4* ep = (const float4*)(edge_attr + (size_t)e * 16);
    float4 f0 = ep[0], f1 = ep[1], f2 = ep[2], f3 = ep[3];
    uint4 a, b;
    a.x = pack_bf(f0.x, f0.y); a.y = pack_bf(f0.z, f0.w);
    a.z = pack_bf(f1.x, f1.y); a.w = pack_bf(f1.z, f1.w);
    b.x = pack_bf(f2.x, f2.y); b.y = pack_bf(f2.z, f2.w);
    b.z = pack_bf(f3.x, f3.y); b.w = pack_bf(f3.z, f3.w);
    eab[(size_t)p * 2]     = a;
    eab[(size_t)p * 2 + 1] = b;
  }
}

// -------- main fused kernel (frozen at R9 — k_kv deltas < noise band) ------
__global__ __launch_bounds__(512, 6)
void k_kv(const unsigned short* __restrict__ hb, const float* __restrict__ coord,
          const float* __restrict__ bkv, const float* __restrict__ b1,
          const float* __restrict__ W2, const float* __restrict__ rnorm,
          const unsigned* __restrict__ rcp, const uint4* __restrict__ eab,
          const unsigned short* __restrict__ Bkvb,
          const unsigned short* __restrict__ W1tb,
          const unsigned short* __restrict__ qg2,
          float* __restrict__ exg, float* __restrict__ l_g,
          float* __restrict__ hacc_g, float* __restrict__ cacc_g) {
  __shared__ __align__(16) unsigned short sA[128][104];   // feat bf16; later v + cd
  __shared__ __align__(16) unsigned short sB[128][104];   // [k|v]^T bf16; later W1^T
  __shared__ unsigned sRC[128];                           // row<<16 | col
  unsigned short (*sW1t)[88] = (unsigned short (*)[88])&sB[0][0];

  const int tid = threadIdx.x;
  const int base = blockIdx.x * 128;

  // prefetch W1^T (11,264 B) into registers; parked into sB's space post-GEMM1
  const uint4* gw = (const uint4*)W1tb;
  uint4 w1a = gw[tid];                 // 704 uint4 total; tid<512 all valid
  uint4 w1b;
  if (tid < 192) w1b = gw[512 + tid];

  if (tid < 128) sRC[tid] = rcp[base + tid];        // for post-GEMM phases
  if (tid < 256) {                                  // edge_attr bf16, coalesced
    int s = tid >> 1;
    *(uint4*)&sA[s][80 + (tid & 1) * 8] = eab[(size_t)base * 2 + tid];
  }
  // hb gather starts immediately — col from rcp directly (8-way uniform)
  for (int idx = tid; idx < 1024; idx += 512) {
    int s = idx >> 3, k8 = idx & 7;
    unsigned c = rcp[base + s] & 0xffffu;
    uint4 u = ((const uint4*)(hb + (size_t)c * 64))[k8];
    *(uint4*)&sA[s][16 + k8 * 8] = u;
  }
  {
    const uint4* gb = (const uint4*)Bkvb;
    uint4* sb = (uint4*)&sB[0][0];
    for (int idx = tid; idx < 1664; idx += 512) sb[idx] = gb[idx];
  }
  const int wv = tid >> 6, lane = tid & 63;
  float cdp[4];   // this wave's coord_diff values, parked to LDS after GEMM1
  {
    const int grp = lane >> 4, g = lane & 15;
    const int c4 = g >> 2, f4 = g & 3;
    const float rn = rnorm[g];
#pragma unroll
    for (int it = 0; it < 4; ++it) {
      int slot = 16 * wv + it * 4 + grp;
      unsigned rc = rcp[base + slot];               // uniform per 16-lane group
      int r = (int)(rc >> 16), c = (int)(rc & 0xffffu);
      float cd = 0.f;
      if (g < 12) cd = coord[r * 12 + g] - coord[c * 12 + g];
      cdp[it] = cd;
      float rad = 0.f;
#pragma unroll
      for (int d = 0; d < 3; ++d)
        rad += __shfl(cd, grp * 16 + c4 * 3 + d) * __shfl(cd, grp * 16 + f4 * 3 + d);
      sA[slot][g] = bf16_of(rad * rn);
    }
  }
  __syncthreads();   // single staging barrier: sA + sB + sRC all visible

  const int m16 = lane & 15, quad = lane >> 4;
  const int arow = 16 * wv + m16;

  // kv = feat @ [Wk|Wv]
  floatx4 acc[8];
#pragma unroll
  for (int i = 0; i < 8; ++i) acc[i] = (floatx4){0.f, 0.f, 0.f, 0.f};
#pragma unroll
  for (int ks = 0; ks < 3; ++ks) {
    short8 af = *(const short8*)&sA[arow][ks * 32 + quad * 8];
#pragma unroll
    for (int nt = 0; nt < 8; ++nt) {
      short8 bf = *(const short8*)&sB[nt * 16 + m16][ks * 32 + quad * 8];
      acc[nt] = __builtin_amdgcn_mfma_f32_16x16x32_bf16(af, bf, acc[nt], 0, 0, 0);
    }
  }
#pragma unroll
  for (int nt = 0; nt < 4; ++nt) {
    float bk = bkv[2 * (m16 + 16 * nt)];
    float bv = bkv[2 * (m16 + 16 * nt) + 1];
#pragma unroll
    for (int r = 0; r < 4; ++r) { acc[nt][r] += bk; acc[nt + 4][r] += bv; }
  }
  // alpha = q . k -> ex = exp(alpha)   (no max stabilizer: |alpha| << 88)
  float part[4] = {0.f, 0.f, 0.f, 0.f};
#pragma unroll
  for (int r = 0; r < 4; ++r) {
    unsigned nrow = sRC[16 * wv + quad * 4 + r] >> 16;
    uint2 qp = *(const uint2*)(qg2 + (size_t)nrow * 64 + m16 * 4);
    part[r] += blo(qp.x) * acc[0][r] + bhi(qp.x) * acc[1][r] +
               blo(qp.y) * acc[2][r] + bhi(qp.y) * acc[3][r];
  }
#pragma unroll
  for (int off = 1; off < 16; off <<= 1) {
#pragma unroll
    for (int r = 0; r < 4; ++r) part[r] += __shfl_xor(part[r], off);
  }
  float ex[4];
#pragma unroll
  for (int r = 0; r < 4; ++r) ex[r] = __expf(part[r]);
  if (m16 == 0) {
#pragma unroll
    for (int r = 0; r < 4; ++r)
      exg[base + 16 * wv + quad * 4 + r] = ex[r];
  }
  // v (bf16) -> sA rows (wave-private) for the W1 GEMM; keep fp32 v in acc[4..7]
#pragma unroll
  for (int nt = 0; nt < 4; ++nt)
#pragma unroll
    for (int r = 0; r < 4; ++r)
      sA[16 * wv + quad * 4 + r][m16 + 16 * nt] = bf16_of(acc[4 + nt][r]);
  // park coord_diff in sA cols 64..75 (dead after this wave's own A-reads)
#pragma unroll
  for (int it = 0; it < 4; ++it)
    if (m16 < 12) sA[16 * wv + it * 4 + quad][64 + m16] = bf16_of(cdp[it]);

  __syncthreads();   // all waves done reading sB (GEMM1)
  {                  // overlay W1^T into sB's space from prefetched regs
    unsigned short* sw = &sB[0][0];
    *(uint4*)&sw[(size_t)tid * 8] = w1a;
    if (tid < 192) *(uint4*)&sw[(size_t)(512 + tid) * 8] = w1b;
  }
  __syncthreads();   // sW1t visible

  // t = silu(v @ W1 + b1)
  floatx4 tacc[4];
#pragma unroll
  for (int i = 0; i < 4; ++i) tacc[i] = (floatx4){0.f, 0.f, 0.f, 0.f};
#pragma unroll
  for (int ks = 0; ks < 2; ++ks) {
    short8 af = *(const short8*)&sA[arow][ks * 32 + quad * 8];
#pragma unroll
    for (int nt = 0; nt < 4; ++nt) {
      short8 bf = *(const short8*)&sW1t[nt * 16 + m16][ks * 32 + quad * 8];
      tacc[nt] = __builtin_amdgcn_mfma_f32_16x16x32_bf16(af, bf, tacc[nt], 0, 0, 0);
    }
  }
#pragma unroll
  for (int nt = 0; nt < 4; ++nt) {
    float bb = b1[m16 + 16 * nt];
#pragma unroll
    for (int r = 0; r < 4; ++r) {
      float t = tacc[nt][r] + bb;
      tacc[nt][r] = t * __builtin_amdgcn_rcpf(1.f + __expf(-t));  // silu, rcp
    }
  }
  // cv = t @ W2 : local partials, then 16-lane REDUCE-SCATTER (15 shfl)
  float w0[16];   // j = r*4+c
#pragma unroll
  for (int r = 0; r < 4; ++r)
#pragma unroll
    for (int c = 0; c < 4; ++c) w0[r * 4 + c] = 0.f;
#pragma unroll
  for (int nt = 0; nt < 4; ++nt) {
    float4 w2r = ((const float4*)W2)[m16 + 16 * nt];
#pragma unroll
    for (int r = 0; r < 4; ++r) {
      w0[r * 4 + 0] += tacc[nt][r] * w2r.x;
      w0[r * 4 + 1] += tacc[nt][r] * w2r.y;
      w0[r * 4 + 2] += tacc[nt][r] * w2r.z;
      w0[r * 4 + 3] += tacc[nt][r] * w2r.w;
    }
  }
  float rs1[8];
#pragma unroll
  for (int jj = 0; jj < 8; ++jj) {
    float snd = (m16 & 8) ? w0[jj] : w0[jj + 8];
    float rcv = __shfl_xor(snd, 8);
    rs1[jj] = ((m16 & 8) ? w0[jj + 8] : w0[jj]) + rcv;
  }
  float rs2[4];
#pragma unroll
  for (int jj = 0; jj < 4; ++jj) {
    float snd = (m16 & 4) ? rs1[jj] : rs1[jj + 4];
    float rcv = __shfl_xor(snd, 4);
    rs2[jj] = ((m16 & 4) ? rs1[jj + 4] : rs1[jj]) + rcv;
  }
  float rs3[2];
#pragma unroll
  for (int jj = 0; jj < 2; ++jj) {
    float snd = (m16 & 2) ? rs2[jj] : rs2[jj + 2];
    float rcv = __shfl_xor(snd, 2);
    rs3[jj] = ((m16 & 2) ? rs2[jj + 2] : rs2[jj]) + rcv;
  }
  float cvtot;
  {
    float snd = (m16 & 1) ? rs3[0] : rs3[1];
    float rcv = __shfl_xor(snd, 1);
    cvtot = ((m16 & 1) ? rs3[1] : rs3[0]) + rcv;
  }
  // lane m16 holds cv[r=m16>>2][c=m16&3]; lane d wants channel d/3
  const int d3 = (m16 < 12) ? ((m16 * 11) >> 5) : 3;
  float tr[4];
#pragma unroll
  for (int r = 0; r < 4; ++r) {
    float cvv = __shfl(cvtot, (quad << 4) + r * 4 + d3);
    tr[r] = (m16 < 12) ? bf2f(sA[16 * wv + quad * 4 + r][64 + m16]) * cvv : 0.f;
  }

  // ---- per-wave segment reduce over this wave's 16 slots + atomics ----
  int s = 0;
  while (s < 16) {
    int n = (int)(sRC[16 * wv + s] >> 16);        // uniform (broadcast)
    int e2 = s + 1;
    while (e2 < 16 && (int)(sRC[16 * wv + e2] >> 16) == n) ++e2;
    float hp0 = 0.f, hp1 = 0.f, hp2 = 0.f, hp3 = 0.f, lp = 0.f, cp = 0.f;
#pragma unroll
    for (int r = 0; r < 4; ++r) {
      int rowi = quad * 4 + r;
      float w = (rowi >= s && rowi < e2) ? ex[r] : 0.f;
      hp0 += w * acc[4][r];
      hp1 += w * acc[5][r];
      hp2 += w * acc[6][r];
      hp3 += w * acc[7][r];
      lp  += (rowi >= s && rowi < e2) ? ex[r] : 0.f;
      cp  += w * tr[r];
    }
    hp0 += __shfl_xor(hp0, 16); hp0 += __shfl_xor(hp0, 32);
    hp1 += __shfl_xor(hp1, 16); hp1 += __shfl_xor(hp1, 32);
    hp2 += __shfl_xor(hp2, 16); hp2 += __shfl_xor(hp2, 32);
    hp3 += __shfl_xor(hp3, 16); hp3 += __shfl_xor(hp3, 32);
    lp  += __shfl_xor(lp, 16);  lp  += __shfl_xor(lp, 32);
    cp  += __shfl_xor(cp, 16);  cp  += __shfl_xor(cp, 32);
    if (quad == 0) {
      float* hg = hacc_g + (size_t)n * 64;
      atomicAdd(hg + m16,      hp0);
      atomicAdd(hg + m16 + 16, hp1);
      atomicAdd(hg + m16 + 32, hp2);
      atomicAdd(hg + m16 + 48, hp3);
      if (m16 < 12) atomicAdd(cacc_g + (size_t)n * 12 + m16, cp);
      if (m16 == 0) atomicAdd(l_g + n, lp);
    }
    s = e2;
  }
}

// ---------------- finalize (float4-granular: 16 threads/node) ----------------
// grid = NN/16 = 3125 blocks x 256; att coverage e in [0, 3125*256) == NE.
__global__ __launch_bounds__(256)
void k_fin(const float* __restrict__ h, const float* __restrict__ coord,
           const int* __restrict__ row, const int* __restrict__ iperm,
           const float* __restrict__ exg, const float* __restrict__ l_g,
           const float* __restrict__ hacc_g, const float* __restrict__ cacc_g,
           float* __restrict__ out) {
  const int node = blockIdx.x * 16 + (threadIdx.x >> 4);
  const int q16 = threadIdx.x & 15;
  const float l = l_g[node];
  const float inv = (l > 0.f) ? 1.f / l : 0.f;
  {
    float4 hv = ((const float4*)(h + (size_t)node * 64))[q16];
    float4 av = ((const float4*)(hacc_g + (size_t)node * 64))[q16];
    float4 o;
    o.x = hv.x + av.x * inv; o.y = hv.y + av.y * inv;
    o.z = hv.z + av.z * inv; o.w = hv.w + av.w * inv;
    ((float4*)(out + (size_t)node * 64))[q16] = o;
  }
  if (q16 < 3) {
    float4 cv = ((const float4*)(coord + (size_t)node * 12))[q16];
    float4 av = ((const float4*)(cacc_g + (size_t)node * 12))[q16];
    float4 o;
    o.x = cv.x + av.x * inv; o.y = cv.y + av.y * inv;
    o.z = cv.z + av.z * inv; o.w = cv.w + av.w * inv;
    ((float4*)(out + (size_t)NN * 64 + (size_t)node * 12))[q16] = o;
  }
  const int e = blockIdx.x * 256 + threadIdx.x;   // covers [0, NE) exactly
  float le = l_g[row[e]];                          // node with an edge: le > 0
  out[(size_t)NN * 64 + NN * 12 + e] = exg[iperm[e]] * __builtin_amdgcn_rcpf(le);
}

extern "C" void kernel_launch(void* const* d_in, const int* in_sizes, int n_in,
                              void* d_out, int out_size, void* d_ws, size_t ws_size,
                              hipStream_t stream) {
  const float* h         = (const float*)d_in[0];
  const float* coord     = (const float*)d_in[1];
  const int*   row       = (const int*)d_in[2];
  const int*   col       = (const int*)d_in[3];
  const float* edge_attr = (const float*)d_in[4];
  const float* Wq        = (const float*)d_in[5];
  const float* bq        = (const float*)d_in[6];
  const float* Wkv       = (const float*)d_in[7];
  const float* bkv       = (const float*)d_in[8];
  const float* W1        = (const float*)d_in[9];
  const float* b1        = (const float*)d_in[10];
  const float* W2        = (const float*)d_in[11];
  float* out = (float*)d_out;

  size_t off = 0;
  char* wsb = (char*)d_ws;
  auto alloc = [&](size_t bytes) {
    off = (off + 255) & ~(size_t)255;
    void* p = wsb + off; off += bytes; return p;
  };
  // ---- zeroed region (contiguous, one memset) ----
  int*            deg      = (int*)alloc((size_t)NN * 4);
  float*          l_g      = (float*)alloc((size_t)NN * 4);
  float*          hacc_g   = (float*)alloc((size_t)NN * 64 * 4);
  float*          cacc_g   = (float*)alloc((size_t)NN * 12 * 4);
  size_t zbytes = off;
  // ---- rest ----
  float*          norm_part= (float*)alloc((size_t)NPREB * 16 * 4);
  float*          rnorm    = (float*)alloc(16 * 4);
  int*            cursor   = (int*)alloc((size_t)NN * 4);
  unsigned*       rcp      = (unsigned*)alloc((size_t)NE * 4);
  int*            iperm    = (int*)alloc((size_t)NE * 4);
  float*          exg      = (float*)alloc((size_t)NE * 4);
  uint4*          eab      = (uint4*)alloc((size_t)NE * 32);
  unsigned short* qg2      = (unsigned short*)alloc((size_t)NN * 64 * 2);
  unsigned short* hb       = (unsigned short*)alloc((size_t)NN * 64 * 2);
  unsigned short* Bkvb     = (unsigned short*)alloc(128 * 104 * 2);
  unsigned short* W1tb     = (unsigned short*)alloc(64 * 88 * 2);
  unsigned*       Wqp      = (unsigned*)alloc(32 * 64 * 4);

  hipMemsetAsync(d_ws, 0, zbytes, stream);

  k_pre<<<NPREB, 256, 0, stream>>>(coord, row, col, Wkv, W1, Wq,
                                   norm_part, deg, Bkvb, W1tb, Wqp);
  k_scanq<<<1 + NN / 16, 1024, 0, stream>>>(deg, cursor, norm_part,
                                            rnorm, h, Wqp, bq, qg2, hb);
  k_scatter<<<(NE + 255) / 256, 256, 0, stream>>>(row, col, edge_attr, cursor,
                                                  iperm, rcp, eab);
  k_kv<<<NE / 128, 512, 0, stream>>>(hb, coord, bkv, b1, W2, rnorm,
                                     rcp, eab, Bkvb, W1tb, qg2,
                                     exg, l_g, hacc_g, cacc_g);
  k_fin<<<NN / 16, 256, 0, stream>>>(h, coord, row, iperm, exg, l_g,
                                     hacc_g, cacc_g, out);
}